// Round 4
// baseline (295.176 us; speedup 1.0000x reference)
//
// GRUCell2 MI355X — r12: XCD-batch-sliced L2-resident gather.
// r11 post-mortem: more in-flight loads was a null -> gather is memory-system
// bound, not MLP-bound. 32MB fp16 table >> 4MiB/XCD L2 -> 140MB re-fetch per
// dispatch. Fix: ONE BATCH PER XCD. fp16 slice of one batch = NP*32*2 = 4MB =
// exactly one XCD's L2. batch = blockIdx.x & 7 rides the round-robin
// blockIdx->XCD dispatch, so each XCD gathers only from its own L2-resident
// slice. Layout stays [b][p][f] (prepass = pure fp32->fp16 convert, no
// transpose). 64B/edge; wave covers 8 edges/instruction (lane = eslot*8+fq);
// per-channel cross-slot reduce = 3-level shfl_xor butterfly.
// bounds[NC+1] precomputed in prepass (kills the per-block 19-dependent-load
// binary search, previously redundant x8 across batches). out uses
// non-temporal stores to protect the L2 slice from the 32MB write stream.
// Bounded downside: if blockIdx%8 != XCD, locality degrades to r11 level.
#include <hip/hip_runtime.h>
#include <hip/hip_fp16.h>

#define NB 8
#define NP 65536
#define NC 32768
#define NF 32
#define NE 524288
#define XROW 40   // shorts per LDS row (80B): 16B-aligned b128 reads, 2-way banks max
#define CHB 64    // channels per block (new kernel): 16 per wave
#define CONV_BLOCKS 8192   // (NB*NP*NF / 8) / 256

typedef __attribute__((ext_vector_type(4))) float floatx4;
typedef __attribute__((ext_vector_type(8))) short short8;
typedef __attribute__((ext_vector_type(4))) short short4v;

struct h4 { __half2 lo, hi; };          // 8B: one global_load_dwordx2
struct h8 { __half2 a, b, c, d; };      // 16B

__device__ __forceinline__ floatx4 h4tof4(h4 v) {
    float2 a = __half22float2(v.lo);
    float2 b = __half22float2(v.hi);
    floatx4 r; r[0] = a.x; r[1] = a.y; r[2] = b.x; r[3] = b.y;
    return r;
}

__device__ __forceinline__ short f2b(float f) {
    union { float f; unsigned int u; } v;
    v.f = f;
    unsigned int lsb = (v.u >> 16) & 1u;
    v.u += 0x7fffu + lsb;   // round-to-nearest-even
    return (short)(v.u >> 16);
}

__device__ __forceinline__ int lower_bound(const int* __restrict__ a, int v) {
    int lo = 0, hi = NE;
    while (lo < hi) {
        int mid = (lo + hi) >> 1;
        if (a[mid] < v) lo = mid + 1; else hi = mid;
    }
    return lo;
}

__device__ __forceinline__ float sigmoidf_(float v) {
    return 1.f / (1.f + __expf(-v));
}
__device__ __forceinline__ float tanhf_(float v) {
    v = fminf(v, 40.f);
    float t = __expf(2.f * v);
    return (t - 1.f) / (t + 1.f);
}

// ---------------------------------------------------------------------------
// Prepass (one kernel, two parts by blockIdx):
//   blocks [0, CONV_BLOCKS): pathH[i] = fp16(path[i])  (pure streaming convert)
//   blocks [CONV_BLOCKS, +129): bounds[c] = lower_bound(edge_channel, c)
// ---------------------------------------------------------------------------
__global__ __launch_bounds__(256) void prep_kernel(
    const float* __restrict__ path, __half* __restrict__ pathH,
    const int* __restrict__ edge_channel, int* __restrict__ bounds)
{
    if (blockIdx.x < CONV_BLOCKS) {
        const size_t id = ((size_t)blockIdx.x * 256 + threadIdx.x) * 8;
        floatx4 v0 = *(const floatx4*)(path + id);
        floatx4 v1 = *(const floatx4*)(path + id + 4);
        h8 o;
        o.a = __floats2half2_rn(v0[0], v0[1]);
        o.b = __floats2half2_rn(v0[2], v0[3]);
        o.c = __floats2half2_rn(v1[0], v1[1]);
        o.d = __floats2half2_rn(v1[2], v1[3]);
        *(h8*)(pathH + id) = o;
    } else {
        const int c = (blockIdx.x - CONV_BLOCKS) * 256 + threadIdx.x;
        if (c <= NC) bounds[c] = lower_bound(edge_channel, c);
    }
}

// ---------------------------------------------------------------------------
// Fused gather + GRU, batch-sliced. Block = 1 batch x 64 channels.
// Phase 1: wave w gathers channels [c0+16w, c0+16w+16); 8 edges per wave-load
// (lane = eslot*8 + fq, 8B/lane = 64B/edge); fp32 slot accum; butterfly
// reduce over lane bits 3..5. Phase 2: r11's verified MFMA GRU, rows =
// 64 contiguous (batch, c0+r) -> fully coalesced h reads / out writes.
// ---------------------------------------------------------------------------
__global__ __launch_bounds__(256) void fused_gru_new(
    const __half* __restrict__ pathH,        // [B,P,F] fp16 (d_ws)
    const float*  __restrict__ hbuf,         // [B,C,F] fp32
    const float*  __restrict__ W_ih,         // [96,32] fp32
    const float*  __restrict__ W_hh,         // [96,32] fp32
    const float*  __restrict__ b_ih,         // [96]
    const float*  __restrict__ b_hh,         // [96]
    const int*    __restrict__ edge_path,    // [E]
    const int*    __restrict__ bounds,       // [NC+1] (d_ws)
    float*        __restrict__ out)          // [B,C,F] fp32
{
    const int t    = threadIdx.x;
    const int w    = t >> 6;      // wave 0..3
    const int lane = t & 63;
    const int batch = blockIdx.x & 7;            // == XCD id under %8 dispatch
    const int c0    = (blockIdx.x >> 3) * CHB;

    __shared__ __align__(16) short xs [64 * XROW];   // x rows bf16, r = c - c0
    __shared__ __align__(16) short wsx[96 * XROW];   // W_ih bf16
    __shared__ __align__(16) short wsh[96 * XROW];   // W_hh bf16

    // Stage weights -> LDS bf16 once per block (24KB, L2-hot).
    for (int idx = t; idx < 96 * NF; idx += 256) {
        int r = idx >> 5, c = idx & 31;
        wsx[r * XROW + c] = f2b(W_ih[idx]);
        wsh[r * XROW + c] = f2b(W_hh[idx]);
    }

    // ---- Phase 1: gather from this batch's 4MB L2-resident slice.
    const int eslot = lane >> 3;     // edge slot 0..7
    const int fq    = lane & 7;      // feature quad: features fq*4..fq*4+3
    const __half* pbase = pathH + (size_t)batch * (NP * NF) + fq * 4;

    for (int j = 0; j < 16; ++j) {
        const int r = w * 16 + j;
        const int c = c0 + r;
        const int s = __builtin_amdgcn_readfirstlane(bounds[c]);
        const int e = __builtin_amdgcn_readfirstlane(bounds[c + 1]);
        floatx4 acc = {0.f, 0.f, 0.f, 0.f};
        for (int i = s; i < e; i += 8) {
            const int idx  = i + eslot;
            const int idxc = idx < e ? idx : e - 1;     // clamp (e>s here)
            const int p    = edge_path[idxc];
            union { h4 g; uint2 u; } gv;
            gv.g = *(const h4*)(pbase + (size_t)p * NF);
            if (idx >= e) { gv.u.x = 0u; gv.u.y = 0u; } // mask tail slots
            acc += h4tof4(gv.g);
        }
        // reduce the 8 edge-slots (lane bits 3..5)
        #pragma unroll
        for (int m = 8; m <= 32; m <<= 1) {
            acc[0] += __shfl_xor(acc[0], m);
            acc[1] += __shfl_xor(acc[1], m);
            acc[2] += __shfl_xor(acc[2], m);
            acc[3] += __shfl_xor(acc[3], m);
        }
        if (eslot == 0) {
            short4v xb;
            #pragma unroll
            for (int q = 0; q < 4; ++q) xb[q] = f2b(acc[q]);
            *(short4v*)(&xs[r * XROW + fq * 4]) = xb;
        }
    }
    __syncthreads();

    // ---- Phase 2: fused GRU via mfma_f32_16x16x32_bf16 (r11-verified).
    const int quad = lane >> 4;
    const int n16  = lane & 15;
    const int k0   = quad * 8;

    const int rA = w * 16 + n16;
    short8 ax = *(const short8*)(&xs[rA * XROW + k0]);

    const size_t mrow = (size_t)batch * NC + c0;     // block's first row
    const float* hrow = hbuf + (mrow + rA) * NF + k0;
    floatx4 h0 = *(const floatx4*)(hrow);
    floatx4 h1 = *(const floatx4*)(hrow + 4);
    short8 ah;
    #pragma unroll
    for (int q = 0; q < 4; ++q) { ah[q] = f2b(h0[q]); ah[4 + q] = f2b(h1[q]); }

    float bxv[6], bhv[6];
    #pragma unroll
    for (int tt = 0; tt < 6; ++tt) {
        bxv[tt] = b_ih[16 * tt + n16];
        bhv[tt] = b_hh[16 * tt + n16];
    }

    const floatx4 zero = {0.f, 0.f, 0.f, 0.f};
    // r,z gates: x- and h-MFMAs chain into ONE accumulator. n gate needs
    // xn and hn separate (r gates hn).
    floatx4 g[4];
    #pragma unroll
    for (int tt = 0; tt < 4; ++tt) {
        short8 bw = *(const short8*)(&wsx[(16 * tt + n16) * XROW + k0]);
        floatx4 a = __builtin_amdgcn_mfma_f32_16x16x32_bf16(ax, bw, zero, 0, 0, 0);
        bw = *(const short8*)(&wsh[(16 * tt + n16) * XROW + k0]);
        g[tt] = __builtin_amdgcn_mfma_f32_16x16x32_bf16(ah, bw, a, 0, 0, 0);
    }
    floatx4 nx[2], nh[2];
    #pragma unroll
    for (int u = 0; u < 2; ++u) {
        const int tt = 4 + u;
        short8 bw = *(const short8*)(&wsx[(16 * tt + n16) * XROW + k0]);
        nx[u] = __builtin_amdgcn_mfma_f32_16x16x32_bf16(ax, bw, zero, 0, 0, 0);
        bw = *(const short8*)(&wsh[(16 * tt + n16) * XROW + k0]);
        nh[u] = __builtin_amdgcn_mfma_f32_16x16x32_bf16(ah, bw, zero, 0, 0, 0);
    }

    // Epilogue in C-layout (col = lane&15, row = quad*4+i), fp32 h blend.
    // Non-temporal out stores: keep the 32MB write stream out of the L2 slice.
    #pragma unroll
    for (int i = 0; i < 4; ++i) {
        const int r2 = w * 16 + quad * 4 + i;
        const size_t m = mrow + r2;
        float r0 = sigmoidf_(g[0][i] + bxv[0] + bhv[0]);
        float r1 = sigmoidf_(g[1][i] + bxv[1] + bhv[1]);
        float z0 = sigmoidf_(g[2][i] + bxv[2] + bhv[2]);
        float z1 = sigmoidf_(g[3][i] + bxv[3] + bhv[3]);
        float n0 = tanhf_(nx[0][i] + bxv[4] + r0 * (nh[0][i] + bhv[4]));
        float n1 = tanhf_(nx[1][i] + bxv[5] + r1 * (nh[1][i] + bhv[5]));
        float hv0 = hbuf[m * NF + n16];
        float hv1 = hbuf[m * NF + 16 + n16];
        __builtin_nontemporal_store((1.f - z0) * n0 + z0 * hv0, &out[m * NF + n16]);
        __builtin_nontemporal_store((1.f - z1) * n1 + z1 * hv1, &out[m * NF + 16 + n16]);
    }
}

// ---------------------------------------------------------------------------
// Fallback (ws too small): r11's verified fp32-gather fused kernel,
// 8 channels/block, in-kernel binary search.
// ---------------------------------------------------------------------------
__global__ __launch_bounds__(256) void fused_gru_fb(
    const float*  __restrict__ path,
    const float*  __restrict__ hbuf,
    const float*  __restrict__ W_ih,
    const float*  __restrict__ W_hh,
    const float*  __restrict__ b_ih,
    const float*  __restrict__ b_hh,
    const int*    __restrict__ edge_path,
    const int*    __restrict__ edge_channel,
    float*        __restrict__ out)
{
    const int t    = threadIdx.x;
    const int w    = t >> 6;
    const int lane = t & 63;
    const int cblk = blockIdx.x * 8;

    __shared__ int bounds[9];
    __shared__ __align__(16) short xs [64 * XROW];
    __shared__ __align__(16) short wsx[96 * XROW];
    __shared__ __align__(16) short wsh[96 * XROW];

    if (t < 9) bounds[t] = lower_bound(edge_channel, cblk + t);
    for (int idx = t; idx < 96 * NF; idx += 256) {
        int r = idx >> 5, c = idx & 31;
        wsx[r * XROW + c] = f2b(W_ih[idx]);
        wsh[r * XROW + c] = f2b(W_hh[idx]);
    }
    __syncthreads();

    const int b  = lane >> 3;
    const int fq = lane & 7;
    const float* prow = path + (size_t)b * (NP * NF) + fq * 4;

    #pragma unroll
    for (int half = 0; half < 2; ++half) {
        const int cl = w * 2 + half;
        const int s = __builtin_amdgcn_readfirstlane(bounds[cl]);
        const int e = __builtin_amdgcn_readfirstlane(bounds[cl + 1]);
        floatx4 acc = {0.f, 0.f, 0.f, 0.f};
        int i = s;
        for (; i + 8 <= e; i += 8) {
            int p0 = edge_path[i + 0], p1 = edge_path[i + 1];
            int p2 = edge_path[i + 2], p3 = edge_path[i + 3];
            int p4 = edge_path[i + 4], p5 = edge_path[i + 5];
            int p6 = edge_path[i + 6], p7 = edge_path[i + 7];
            floatx4 g0 = *(const floatx4*)(prow + (size_t)p0 * NF);
            floatx4 g1 = *(const floatx4*)(prow + (size_t)p1 * NF);
            floatx4 g2 = *(const floatx4*)(prow + (size_t)p2 * NF);
            floatx4 g3 = *(const floatx4*)(prow + (size_t)p3 * NF);
            floatx4 g4 = *(const floatx4*)(prow + (size_t)p4 * NF);
            floatx4 g5 = *(const floatx4*)(prow + (size_t)p5 * NF);
            floatx4 g6 = *(const floatx4*)(prow + (size_t)p6 * NF);
            floatx4 g7 = *(const floatx4*)(prow + (size_t)p7 * NF);
            acc += ((g0 + g1) + (g2 + g3)) + ((g4 + g5) + (g6 + g7));
        }
        for (; i < e; ++i)
            acc += *(const floatx4*)(prow + (size_t)edge_path[i] * NF);
        short4v xb;
        #pragma unroll
        for (int q = 0; q < 4; ++q) xb[q] = f2b(acc[q]);
        *(short4v*)(&xs[(b * 8 + cl) * XROW + fq * 4]) = xb;
    }
    __syncthreads();

    const int quad = lane >> 4;
    const int n16  = lane & 15;
    const int k0   = quad * 8;

    const int rA = w * 16 + n16;
    short8 ax = *(const short8*)(&xs[rA * XROW + k0]);
    const int bA = rA >> 3;
    const int cA = cblk + (rA & 7);
    const float* hrow = hbuf + ((size_t)bA * NC + cA) * NF + k0;
    floatx4 h0 = *(const floatx4*)(hrow);
    floatx4 h1 = *(const floatx4*)(hrow + 4);
    short8 ah;
    #pragma unroll
    for (int q = 0; q < 4; ++q) { ah[q] = f2b(h0[q]); ah[4 + q] = f2b(h1[q]); }

    float bxv[6], bhv[6];
    #pragma unroll
    for (int tt = 0; tt < 6; ++tt) {
        bxv[tt] = b_ih[16 * tt + n16];
        bhv[tt] = b_hh[16 * tt + n16];
    }
    const floatx4 zero = {0.f, 0.f, 0.f, 0.f};
    floatx4 g[4];
    #pragma unroll
    for (int tt = 0; tt < 4; ++tt) {
        short8 bw = *(const short8*)(&wsx[(16 * tt + n16) * XROW + k0]);
        floatx4 a = __builtin_amdgcn_mfma_f32_16x16x32_bf16(ax, bw, zero, 0, 0, 0);
        bw = *(const short8*)(&wsh[(16 * tt + n16) * XROW + k0]);
        g[tt] = __builtin_amdgcn_mfma_f32_16x16x32_bf16(ah, bw, a, 0, 0, 0);
    }
    floatx4 nx[2], nh[2];
    #pragma unroll
    for (int u = 0; u < 2; ++u) {
        const int tt = 4 + u;
        short8 bw = *(const short8*)(&wsx[(16 * tt + n16) * XROW + k0]);
        nx[u] = __builtin_amdgcn_mfma_f32_16x16x32_bf16(ax, bw, zero, 0, 0, 0);
        bw = *(const short8*)(&wsh[(16 * tt + n16) * XROW + k0]);
        nh[u] = __builtin_amdgcn_mfma_f32_16x16x32_bf16(ah, bw, zero, 0, 0, 0);
    }
    #pragma unroll
    for (int i = 0; i < 4; ++i) {
        const int r  = w * 16 + quad * 4 + i;
        const int b2 = r >> 3;
        const size_t m = (size_t)b2 * NC + (cblk + (r & 7));
        float r0 = sigmoidf_(g[0][i] + bxv[0] + bhv[0]);
        float r1 = sigmoidf_(g[1][i] + bxv[1] + bhv[1]);
        float z0 = sigmoidf_(g[2][i] + bxv[2] + bhv[2]);
        float z1 = sigmoidf_(g[3][i] + bxv[3] + bhv[3]);
        float n0 = tanhf_(nx[0][i] + bxv[4] + r0 * (nh[0][i] + bhv[4]));
        float n1 = tanhf_(nx[1][i] + bxv[5] + r1 * (nh[1][i] + bhv[5]));
        float hv0 = hbuf[m * NF + n16];
        float hv1 = hbuf[m * NF + 16 + n16];
        out[m * NF + n16]      = (1.f - z0) * n0 + z0 * hv0;
        out[m * NF + 16 + n16] = (1.f - z1) * n1 + z1 * hv1;
    }
}

extern "C" void kernel_launch(void* const* d_in, const int* in_sizes, int n_in,
                              void* d_out, int out_size, void* d_ws, size_t ws_size,
                              hipStream_t stream) {
    const float* path = (const float*)d_in[0];  // [8,65536,32] fp32
    const float* chan = (const float*)d_in[1];  // [8,32768,32] fp32
    const float* W_ih = (const float*)d_in[2];  // [96,32]
    const float* W_hh = (const float*)d_in[3];  // [96,32]
    const float* b_ih = (const float*)d_in[4];  // [96]
    const float* b_hh = (const float*)d_in[5];  // [96]
    const int* edge_path    = (const int*)d_in[6];
    const int* edge_channel = (const int*)d_in[7];
    float* out = (float*)d_out;                 // [8,32768,32] fp32

    const size_t pathH_bytes = (size_t)NB * NP * NF * sizeof(__half);  // 32MB
    const size_t need = pathH_bytes + (size_t)(NC + 1) * sizeof(int);
    if (ws_size >= need) {
        __half* pathH = (__half*)d_ws;
        int* bounds = (int*)((char*)d_ws + pathH_bytes);
        const int bblocks = (NC + 1 + 255) / 256;    // 129
        prep_kernel<<<dim3(CONV_BLOCKS + bblocks), dim3(256), 0, stream>>>(
            path, pathH, edge_channel, bounds);
        fused_gru_new<<<dim3((NC / CHB) * NB), dim3(256), 0, stream>>>(
            pathH, chan, W_ih, W_hh, b_ih, b_hh, edge_path, bounds, out);
    } else {
        fused_gru_fb<<<dim3(NC / 8), dim3(256), 0, stream>>>(
            path, chan, W_ih, W_hh, b_ih, b_hh, edge_path, edge_channel, out);
    }
}

// Round 5
// 220.221 us; speedup vs baseline: 1.3404x; 1.3404x over previous
//
// GRUCell2 MI355X — r13: batch-per-XCD slicing (r12, kept: FETCH 140->83MB
// confirmed) + lane-private gather accumulation (r12's serialization fixed).
// r12 post-mortem: one channel per wave, 2 loads in flight, 12-shuffle
// butterfly per channel -> latency chain, 730 GB/s, 164us. Fix: wave walks 8
// channels concurrently (lane = chslot*8 + fq); each 8-lane group owns one
// channel and accumulates its own feature quad -> zero cross-lane ops, final
// lane acc IS the xs entry. Edge loop unrolled x8 with predicated tail: 4KB
// in flight per wave at L2 latency (~200cy) ≈ 18KB-at-HBM-latency equivalent.
// Divergent group lengths handled by exec mask (finished groups stop issuing).
// Prep kernel (fp32->fp16 convert + bounds precompute), MFMA GRU phase, and
// non-temporal epilogue carried over unchanged from r12 (verified correct).
#include <hip/hip_runtime.h>
#include <hip/hip_fp16.h>

#define NB 8
#define NP 65536
#define NC 32768
#define NF 32
#define NE 524288
#define XROW 40   // shorts per LDS row (80B): 16B-aligned b128 reads, 2-way banks max
#define CHB 64    // channels per block: 8 per wave-round, 2 rounds, 4 waves
#define CONV_BLOCKS 8192   // (NB*NP*NF / 8) / 256

typedef __attribute__((ext_vector_type(4))) float floatx4;
typedef __attribute__((ext_vector_type(8))) short short8;
typedef __attribute__((ext_vector_type(4))) short short4v;

struct h4 { __half2 lo, hi; };          // 8B: one global_load_dwordx2
struct h8 { __half2 a, b, c, d; };      // 16B

__device__ __forceinline__ floatx4 h4tof4(h4 v) {
    float2 a = __half22float2(v.lo);
    float2 b = __half22float2(v.hi);
    floatx4 r; r[0] = a.x; r[1] = a.y; r[2] = b.x; r[3] = b.y;
    return r;
}

__device__ __forceinline__ short f2b(float f) {
    union { float f; unsigned int u; } v;
    v.f = f;
    unsigned int lsb = (v.u >> 16) & 1u;
    v.u += 0x7fffu + lsb;   // round-to-nearest-even
    return (short)(v.u >> 16);
}

__device__ __forceinline__ int lower_bound(const int* __restrict__ a, int v) {
    int lo = 0, hi = NE;
    while (lo < hi) {
        int mid = (lo + hi) >> 1;
        if (a[mid] < v) lo = mid + 1; else hi = mid;
    }
    return lo;
}

__device__ __forceinline__ float sigmoidf_(float v) {
    return 1.f / (1.f + __expf(-v));
}
__device__ __forceinline__ float tanhf_(float v) {
    v = fminf(v, 40.f);
    float t = __expf(2.f * v);
    return (t - 1.f) / (t + 1.f);
}

// ---------------------------------------------------------------------------
// Prepass (one kernel, two parts by blockIdx):
//   blocks [0, CONV_BLOCKS): pathH[i] = fp16(path[i])  (pure streaming convert)
//   blocks [CONV_BLOCKS, +129): bounds[c] = lower_bound(edge_channel, c)
// ---------------------------------------------------------------------------
__global__ __launch_bounds__(256) void prep_kernel(
    const float* __restrict__ path, __half* __restrict__ pathH,
    const int* __restrict__ edge_channel, int* __restrict__ bounds)
{
    if (blockIdx.x < CONV_BLOCKS) {
        const size_t id = ((size_t)blockIdx.x * 256 + threadIdx.x) * 8;
        floatx4 v0 = *(const floatx4*)(path + id);
        floatx4 v1 = *(const floatx4*)(path + id + 4);
        h8 o;
        o.a = __floats2half2_rn(v0[0], v0[1]);
        o.b = __floats2half2_rn(v0[2], v0[3]);
        o.c = __floats2half2_rn(v1[0], v1[1]);
        o.d = __floats2half2_rn(v1[2], v1[3]);
        *(h8*)(pathH + id) = o;
    } else {
        const int c = (blockIdx.x - CONV_BLOCKS) * 256 + threadIdx.x;
        if (c <= NC) bounds[c] = lower_bound(edge_channel, c);
    }
}

// ---------------------------------------------------------------------------
// Fused gather + GRU, batch-sliced. Block = 1 batch x 64 channels.
// Phase 1: 32 groups of 8 lanes; group owns one channel per round (2 rounds),
// lane accumulates its feature quad privately; unroll-8 edge loop keeps
// 4KB/wave of L2-resident gathers in flight. Phase 2: verified MFMA GRU.
// ---------------------------------------------------------------------------
__global__ __launch_bounds__(256) void fused_gru_new(
    const __half* __restrict__ pathH,        // [B,P,F] fp16 (d_ws)
    const float*  __restrict__ hbuf,         // [B,C,F] fp32
    const float*  __restrict__ W_ih,         // [96,32] fp32
    const float*  __restrict__ W_hh,         // [96,32] fp32
    const float*  __restrict__ b_ih,         // [96]
    const float*  __restrict__ b_hh,         // [96]
    const int*    __restrict__ edge_path,    // [E]
    const int*    __restrict__ bounds,       // [NC+1] (d_ws)
    float*        __restrict__ out)          // [B,C,F] fp32
{
    const int t    = threadIdx.x;
    const int w    = t >> 6;      // wave 0..3
    const int lane = t & 63;
    const int batch = blockIdx.x & 7;            // == XCD id under %8 dispatch
    const int c0    = (blockIdx.x >> 3) * CHB;

    __shared__ __align__(16) short xs [64 * XROW];   // x rows bf16, r = c - c0
    __shared__ __align__(16) short wsx[96 * XROW];   // W_ih bf16
    __shared__ __align__(16) short wsh[96 * XROW];   // W_hh bf16

    // Stage weights -> LDS bf16 once per block (24KB, L2-hot).
    for (int idx = t; idx < 96 * NF; idx += 256) {
        int r = idx >> 5, c = idx & 31;
        wsx[r * XROW + c] = f2b(W_ih[idx]);
        wsh[r * XROW + c] = f2b(W_hh[idx]);
    }

    // ---- Phase 1: gather from this batch's 4MB L2-resident slice.
    const int group = t >> 3;        // 0..31: channel group
    const int fq    = t & 7;         // feature quad: features fq*4..fq*4+3
    const __half* pbase = pathH + (size_t)batch * (NP * NF) + fq * 4;

    #pragma unroll
    for (int rnd = 0; rnd < 2; ++rnd) {
        const int r = rnd * 32 + group;          // xs row / channel offset
        const int c = c0 + r;
        const int s = bounds[c];
        const int e = bounds[c + 1];
        floatx4 acc = {0.f, 0.f, 0.f, 0.f};
        for (int i = s; i < e; i += 8) {         // divergent: exec-masked
            int p0 = edge_path[i];
            int i1 = i + 1, i2 = i + 2, i3 = i + 3;
            int i4 = i + 4, i5 = i + 5, i6 = i + 6, i7 = i + 7;
            int p1 = edge_path[i1 < e ? i1 : s];
            int p2 = edge_path[i2 < e ? i2 : s];
            int p3 = edge_path[i3 < e ? i3 : s];
            int p4 = edge_path[i4 < e ? i4 : s];
            int p5 = edge_path[i5 < e ? i5 : s];
            int p6 = edge_path[i6 < e ? i6 : s];
            int p7 = edge_path[i7 < e ? i7 : s];
            h4 g0 = *(const h4*)(pbase + (size_t)p0 * NF);
            h4 g1 = *(const h4*)(pbase + (size_t)p1 * NF);
            h4 g2 = *(const h4*)(pbase + (size_t)p2 * NF);
            h4 g3 = *(const h4*)(pbase + (size_t)p3 * NF);
            h4 g4 = *(const h4*)(pbase + (size_t)p4 * NF);
            h4 g5 = *(const h4*)(pbase + (size_t)p5 * NF);
            h4 g6 = *(const h4*)(pbase + (size_t)p6 * NF);
            h4 g7 = *(const h4*)(pbase + (size_t)p7 * NF);
            acc += h4tof4(g0);
            if (i1 < e) acc += h4tof4(g1);
            if (i2 < e) acc += h4tof4(g2);
            if (i3 < e) acc += h4tof4(g3);
            if (i4 < e) acc += h4tof4(g4);
            if (i5 < e) acc += h4tof4(g5);
            if (i6 < e) acc += h4tof4(g6);
            if (i7 < e) acc += h4tof4(g7);
        }
        short4v xb;
        #pragma unroll
        for (int q = 0; q < 4; ++q) xb[q] = f2b(acc[q]);
        *(short4v*)(&xs[r * XROW + fq * 4]) = xb;
    }
    __syncthreads();

    // ---- Phase 2: fused GRU via mfma_f32_16x16x32_bf16 (verified).
    const int quad = lane >> 4;
    const int n16  = lane & 15;
    const int k0   = quad * 8;

    const int rA = w * 16 + n16;
    short8 ax = *(const short8*)(&xs[rA * XROW + k0]);

    const size_t mrow = (size_t)batch * NC + c0;     // block's first row
    const float* hrow = hbuf + (mrow + rA) * NF + k0;
    floatx4 h0 = *(const floatx4*)(hrow);
    floatx4 h1 = *(const floatx4*)(hrow + 4);
    short8 ah;
    #pragma unroll
    for (int q = 0; q < 4; ++q) { ah[q] = f2b(h0[q]); ah[4 + q] = f2b(h1[q]); }

    float bxv[6], bhv[6];
    #pragma unroll
    for (int tt = 0; tt < 6; ++tt) {
        bxv[tt] = b_ih[16 * tt + n16];
        bhv[tt] = b_hh[16 * tt + n16];
    }

    const floatx4 zero = {0.f, 0.f, 0.f, 0.f};
    // r,z gates: x- and h-MFMAs chain into ONE accumulator. n gate needs
    // xn and hn separate (r gates hn).
    floatx4 g[4];
    #pragma unroll
    for (int tt = 0; tt < 4; ++tt) {
        short8 bw = *(const short8*)(&wsx[(16 * tt + n16) * XROW + k0]);
        floatx4 a = __builtin_amdgcn_mfma_f32_16x16x32_bf16(ax, bw, zero, 0, 0, 0);
        bw = *(const short8*)(&wsh[(16 * tt + n16) * XROW + k0]);
        g[tt] = __builtin_amdgcn_mfma_f32_16x16x32_bf16(ah, bw, a, 0, 0, 0);
    }
    floatx4 nx[2], nh[2];
    #pragma unroll
    for (int u = 0; u < 2; ++u) {
        const int tt = 4 + u;
        short8 bw = *(const short8*)(&wsx[(16 * tt + n16) * XROW + k0]);
        nx[u] = __builtin_amdgcn_mfma_f32_16x16x32_bf16(ax, bw, zero, 0, 0, 0);
        bw = *(const short8*)(&wsh[(16 * tt + n16) * XROW + k0]);
        nh[u] = __builtin_amdgcn_mfma_f32_16x16x32_bf16(ah, bw, zero, 0, 0, 0);
    }

    // Epilogue in C-layout (col = lane&15, row = quad*4+i), fp32 h blend.
    // Non-temporal out stores: keep the 32MB write stream out of the L2 slice.
    #pragma unroll
    for (int i = 0; i < 4; ++i) {
        const int r2 = w * 16 + quad * 4 + i;
        const size_t m = mrow + r2;
        float r0 = sigmoidf_(g[0][i] + bxv[0] + bhv[0]);
        float r1 = sigmoidf_(g[1][i] + bxv[1] + bhv[1]);
        float z0 = sigmoidf_(g[2][i] + bxv[2] + bhv[2]);
        float z1 = sigmoidf_(g[3][i] + bxv[3] + bhv[3]);
        float n0 = tanhf_(nx[0][i] + bxv[4] + r0 * (nh[0][i] + bhv[4]));
        float n1 = tanhf_(nx[1][i] + bxv[5] + r1 * (nh[1][i] + bhv[5]));
        float hv0 = hbuf[m * NF + n16];
        float hv1 = hbuf[m * NF + 16 + n16];
        __builtin_nontemporal_store((1.f - z0) * n0 + z0 * hv0, &out[m * NF + n16]);
        __builtin_nontemporal_store((1.f - z1) * n1 + z1 * hv1, &out[m * NF + 16 + n16]);
    }
}

// ---------------------------------------------------------------------------
// Fallback (ws too small): r11's verified fp32-gather fused kernel,
// 8 channels/block, in-kernel binary search.
// ---------------------------------------------------------------------------
__global__ __launch_bounds__(256) void fused_gru_fb(
    const float*  __restrict__ path,
    const float*  __restrict__ hbuf,
    const float*  __restrict__ W_ih,
    const float*  __restrict__ W_hh,
    const float*  __restrict__ b_ih,
    const float*  __restrict__ b_hh,
    const int*    __restrict__ edge_path,
    const int*    __restrict__ edge_channel,
    float*        __restrict__ out)
{
    const int t    = threadIdx.x;
    const int w    = t >> 6;
    const int lane = t & 63;
    const int cblk = blockIdx.x * 8;

    __shared__ int bounds[9];
    __shared__ __align__(16) short xs [64 * XROW];
    __shared__ __align__(16) short wsx[96 * XROW];
    __shared__ __align__(16) short wsh[96 * XROW];

    if (t < 9) bounds[t] = lower_bound(edge_channel, cblk + t);
    for (int idx = t; idx < 96 * NF; idx += 256) {
        int r = idx >> 5, c = idx & 31;
        wsx[r * XROW + c] = f2b(W_ih[idx]);
        wsh[r * XROW + c] = f2b(W_hh[idx]);
    }
    __syncthreads();

    const int b  = lane >> 3;
    const int fq = lane & 7;
    const float* prow = path + (size_t)b * (NP * NF) + fq * 4;

    #pragma unroll
    for (int half = 0; half < 2; ++half) {
        const int cl = w * 2 + half;
        const int s = __builtin_amdgcn_readfirstlane(bounds[cl]);
        const int e = __builtin_amdgcn_readfirstlane(bounds[cl + 1]);
        floatx4 acc = {0.f, 0.f, 0.f, 0.f};
        int i = s;
        for (; i + 8 <= e; i += 8) {
            int p0 = edge_path[i + 0], p1 = edge_path[i + 1];
            int p2 = edge_path[i + 2], p3 = edge_path[i + 3];
            int p4 = edge_path[i + 4], p5 = edge_path[i + 5];
            int p6 = edge_path[i + 6], p7 = edge_path[i + 7];
            floatx4 g0 = *(const floatx4*)(prow + (size_t)p0 * NF);
            floatx4 g1 = *(const floatx4*)(prow + (size_t)p1 * NF);
            floatx4 g2 = *(const floatx4*)(prow + (size_t)p2 * NF);
            floatx4 g3 = *(const floatx4*)(prow + (size_t)p3 * NF);
            floatx4 g4 = *(const floatx4*)(prow + (size_t)p4 * NF);
            floatx4 g5 = *(const floatx4*)(prow + (size_t)p5 * NF);
            floatx4 g6 = *(const floatx4*)(prow + (size_t)p6 * NF);
            floatx4 g7 = *(const floatx4*)(prow + (size_t)p7 * NF);
            acc += ((g0 + g1) + (g2 + g3)) + ((g4 + g5) + (g6 + g7));
        }
        for (; i < e; ++i)
            acc += *(const floatx4*)(prow + (size_t)edge_path[i] * NF);
        short4v xb;
        #pragma unroll
        for (int q = 0; q < 4; ++q) xb[q] = f2b(acc[q]);
        *(short4v*)(&xs[(b * 8 + cl) * XROW + fq * 4]) = xb;
    }
    __syncthreads();

    const int quad = lane >> 4;
    const int n16  = lane & 15;
    const int k0   = quad * 8;

    const int rA = w * 16 + n16;
    short8 ax = *(const short8*)(&xs[rA * XROW + k0]);
    const int bA = rA >> 3;
    const int cA = cblk + (rA & 7);
    const float* hrow = hbuf + ((size_t)bA * NC + cA) * NF + k0;
    floatx4 h0 = *(const floatx4*)(hrow);
    floatx4 h1 = *(const floatx4*)(hrow + 4);
    short8 ah;
    #pragma unroll
    for (int q = 0; q < 4; ++q) { ah[q] = f2b(h0[q]); ah[4 + q] = f2b(h1[q]); }

    float bxv[6], bhv[6];
    #pragma unroll
    for (int tt = 0; tt < 6; ++tt) {
        bxv[tt] = b_ih[16 * tt + n16];
        bhv[tt] = b_hh[16 * tt + n16];
    }
    const floatx4 zero = {0.f, 0.f, 0.f, 0.f};
    floatx4 g[4];
    #pragma unroll
    for (int tt = 0; tt < 4; ++tt) {
        short8 bw = *(const short8*)(&wsx[(16 * tt + n16) * XROW + k0]);
        floatx4 a = __builtin_amdgcn_mfma_f32_16x16x32_bf16(ax, bw, zero, 0, 0, 0);
        bw = *(const short8*)(&wsh[(16 * tt + n16) * XROW + k0]);
        g[tt] = __builtin_amdgcn_mfma_f32_16x16x32_bf16(ah, bw, a, 0, 0, 0);
    }
    floatx4 nx[2], nh[2];
    #pragma unroll
    for (int u = 0; u < 2; ++u) {
        const int tt = 4 + u;
        short8 bw = *(const short8*)(&wsx[(16 * tt + n16) * XROW + k0]);
        nx[u] = __builtin_amdgcn_mfma_f32_16x16x32_bf16(ax, bw, zero, 0, 0, 0);
        bw = *(const short8*)(&wsh[(16 * tt + n16) * XROW + k0]);
        nh[u] = __builtin_amdgcn_mfma_f32_16x16x32_bf16(ah, bw, zero, 0, 0, 0);
    }
    #pragma unroll
    for (int i = 0; i < 4; ++i) {
        const int r  = w * 16 + quad * 4 + i;
        const int b2 = r >> 3;
        const size_t m = (size_t)b2 * NC + (cblk + (r & 7));
        float r0 = sigmoidf_(g[0][i] + bxv[0] + bhv[0]);
        float r1 = sigmoidf_(g[1][i] + bxv[1] + bhv[1]);
        float z0 = sigmoidf_(g[2][i] + bxv[2] + bhv[2]);
        float z1 = sigmoidf_(g[3][i] + bxv[3] + bhv[3]);
        float n0 = tanhf_(nx[0][i] + bxv[4] + r0 * (nh[0][i] + bhv[4]));
        float n1 = tanhf_(nx[1][i] + bxv[5] + r1 * (nh[1][i] + bhv[5]));
        float hv0 = hbuf[m * NF + n16];
        float hv1 = hbuf[m * NF + 16 + n16];
        out[m * NF + n16]      = (1.f - z0) * n0 + z0 * hv0;
        out[m * NF + 16 + n16] = (1.f - z1) * n1 + z1 * hv1;
    }
}

extern "C" void kernel_launch(void* const* d_in, const int* in_sizes, int n_in,
                              void* d_out, int out_size, void* d_ws, size_t ws_size,
                              hipStream_t stream) {
    const float* path = (const float*)d_in[0];  // [8,65536,32] fp32
    const float* chan = (const float*)d_in[1];  // [8,32768,32] fp32
    const float* W_ih = (const float*)d_in[2];  // [96,32]
    const float* W_hh = (const float*)d_in[3];  // [96,32]
    const float* b_ih = (const float*)d_in[4];  // [96]
    const float* b_hh = (const float*)d_in[5];  // [96]
    const int* edge_path    = (const int*)d_in[6];
    const int* edge_channel = (const int*)d_in[7];
    float* out = (float*)d_out;                 // [8,32768,32] fp32

    const size_t pathH_bytes = (size_t)NB * NP * NF * sizeof(__half);  // 32MB
    const size_t need = pathH_bytes + (size_t)(NC + 1) * sizeof(int);
    if (ws_size >= need) {
        __half* pathH = (__half*)d_ws;
        int* bounds = (int*)((char*)d_ws + pathH_bytes);
        const int bblocks = (NC + 1 + 255) / 256;    // 129
        prep_kernel<<<dim3(CONV_BLOCKS + bblocks), dim3(256), 0, stream>>>(
            path, pathH, edge_channel, bounds);
        fused_gru_new<<<dim3((NC / CHB) * NB), dim3(256), 0, stream>>>(
            pathH, chan, W_ih, W_hh, b_ih, b_hh, edge_path, bounds, out);
    } else {
        fused_gru_fb<<<dim3(NC / 8), dim3(256), 0, stream>>>(
            path, chan, W_ih, W_hh, b_ih, b_hh, edge_path, edge_channel, out);
    }
}

// Round 6
// 218.084 us; speedup vs baseline: 1.3535x; 1.0098x over previous
//
// GRUCell2 MI355X — r14: r13 (batch-per-XCD sliced gather, lane-private acc)
// + LDS-staged edge indices (kill the index half of the transaction stream)
// + NT hints on all streaming traffic (protect the 4MB L2 path slice).
// Evidence: ~90us invariant across r10/r11/r13 despite FETCH 140->88MB and
// HBM 2.0->1.4 TB/s => fused kernel is bound by memory-REQUEST count, not
// bytes. r13 issues ~2 scattered-line transactions per edge (gather + index).
// A block's indices are one contiguous edge_path range (channels sorted &
// contiguous) -> stage into LDS coalesced once; index reads become broadcast
// ds_reads (zero TCP transactions). Gather drops to the irreducible
// ~1 transaction/edge. NT on h/out/prep streams keeps the path slice
// L2-resident (r12/r13 proved the slicing works: FETCH 140->88MB).
#include <hip/hip_runtime.h>
#include <hip/hip_fp16.h>

#define NB 8
#define NP 65536
#define NC 32768
#define NF 32
#define NE 524288
#define XROW 40   // shorts per LDS row (80B): 16B-aligned b128 reads, 2-way banks max
#define CHB 64    // channels per block: 8 per wave-round, 2 rounds, 4 waves
#define CAP 2048  // staged indices per block (mean 1024, +32 sigma)
#define CONV_BLOCKS 8192   // (NB*NP*NF / 8) / 256

typedef __attribute__((ext_vector_type(4))) float floatx4;
typedef __attribute__((ext_vector_type(8))) short short8;
typedef __attribute__((ext_vector_type(4))) short short4v;

struct h4 { __half2 lo, hi; };          // 8B: one global_load_dwordx2
struct h8 { __half2 a, b, c, d; };      // 16B

__device__ __forceinline__ floatx4 h4tof4(h4 v) {
    float2 a = __half22float2(v.lo);
    float2 b = __half22float2(v.hi);
    floatx4 r; r[0] = a.x; r[1] = a.y; r[2] = b.x; r[3] = b.y;
    return r;
}

__device__ __forceinline__ short f2b(float f) {
    union { float f; unsigned int u; } v;
    v.f = f;
    unsigned int lsb = (v.u >> 16) & 1u;
    v.u += 0x7fffu + lsb;   // round-to-nearest-even
    return (short)(v.u >> 16);
}

__device__ __forceinline__ int lower_bound(const int* __restrict__ a, int v) {
    int lo = 0, hi = NE;
    while (lo < hi) {
        int mid = (lo + hi) >> 1;
        if (a[mid] < v) lo = mid + 1; else hi = mid;
    }
    return lo;
}

__device__ __forceinline__ float sigmoidf_(float v) {
    return 1.f / (1.f + __expf(-v));
}
__device__ __forceinline__ float tanhf_(float v) {
    v = fminf(v, 40.f);
    float t = __expf(2.f * v);
    return (t - 1.f) / (t + 1.f);
}

// ---------------------------------------------------------------------------
// Prepass (one kernel, two parts by blockIdx):
//   blocks [0, CONV_BLOCKS): pathH[i] = fp16(path[i])  (NT streaming convert)
//   blocks [CONV_BLOCKS, +129): bounds[c] = lower_bound(edge_channel, c)
// ---------------------------------------------------------------------------
__global__ __launch_bounds__(256) void prep_kernel(
    const float* __restrict__ path, __half* __restrict__ pathH,
    const int* __restrict__ edge_channel, int* __restrict__ bounds)
{
    if (blockIdx.x < CONV_BLOCKS) {
        const size_t id = ((size_t)blockIdx.x * 256 + threadIdx.x) * 8;
        floatx4 v0 = __builtin_nontemporal_load((const floatx4*)(path + id));
        floatx4 v1 = __builtin_nontemporal_load((const floatx4*)(path + id + 4));
        h8 o;
        o.a = __floats2half2_rn(v0[0], v0[1]);
        o.b = __floats2half2_rn(v0[2], v0[3]);
        o.c = __floats2half2_rn(v1[0], v1[1]);
        o.d = __floats2half2_rn(v1[2], v1[3]);
        union { h8 s; floatx4 f; } cv; cv.s = o;
        __builtin_nontemporal_store(cv.f, (floatx4*)(pathH + id));
    } else {
        const int c = (blockIdx.x - CONV_BLOCKS) * 256 + threadIdx.x;
        if (c <= NC) bounds[c] = lower_bound(edge_channel, c);
    }
}

// ---------------------------------------------------------------------------
// Fused gather + GRU, batch-sliced. Block = 1 batch x 64 channels.
// Phase 0: stage the block's contiguous edge-index range into LDS (coalesced).
// Phase 1: 32 groups of 8 lanes; group owns one channel per round (2 rounds);
// lane accumulates its feature quad privately; indices from LDS (broadcast
// ds_read, zero TCP transactions); unroll-8 keeps 8 gathers/wave in flight.
// Phase 2: verified MFMA GRU; NT h loads / out stores protect the L2 slice.
// ---------------------------------------------------------------------------
__global__ __launch_bounds__(256) void fused_gru_new(
    const __half* __restrict__ pathH,        // [B,P,F] fp16 (d_ws)
    const float*  __restrict__ hbuf,         // [B,C,F] fp32
    const float*  __restrict__ W_ih,         // [96,32] fp32
    const float*  __restrict__ W_hh,         // [96,32] fp32
    const float*  __restrict__ b_ih,         // [96]
    const float*  __restrict__ b_hh,         // [96]
    const int*    __restrict__ edge_path,    // [E]
    const int*    __restrict__ bounds,       // [NC+1] (d_ws)
    float*        __restrict__ out)          // [B,C,F] fp32
{
    const int t    = threadIdx.x;
    const int w    = t >> 6;      // wave 0..3
    const int lane = t & 63;
    const int batch = blockIdx.x & 7;            // == XCD id under %8 dispatch
    const int c0    = (blockIdx.x >> 3) * CHB;

    __shared__ __align__(16) short xs [64 * XROW];   // x rows bf16, r = c - c0
    __shared__ __align__(16) short wsx[96 * XROW];   // W_ih bf16
    __shared__ __align__(16) short wsh[96 * XROW];   // W_hh bf16
    __shared__ int lbnd[CHB + 1];
    __shared__ int eidx[CAP];

    // Stage weights -> LDS bf16 once per block (24KB, L2-hot).
    for (int idx = t; idx < 96 * NF; idx += 256) {
        int r = idx >> 5, c = idx & 31;
        wsx[r * XROW + c] = f2b(W_ih[idx]);
        wsh[r * XROW + c] = f2b(W_hh[idx]);
    }
    if (t <= CHB) lbnd[t] = bounds[c0 + t];

    // Stage this block's contiguous edge-index range (coalesced).
    const int base = bounds[c0];                   // broadcast load
    const int cnt  = bounds[c0 + CHB] - base;
    const int cntc = cnt < CAP ? cnt : CAP;
    for (int j = t; j < cntc; j += 256) eidx[j] = edge_path[base + j];
    __syncthreads();

    // ---- Phase 1: gather from this batch's 4MB L2-resident slice.
    const int group = t >> 3;        // 0..31: channel group
    const int fq    = t & 7;         // feature quad: features fq*4..fq*4+3
    const __half* pbase = pathH + (size_t)batch * (NP * NF) + fq * 4;

    // Gather loop body, parameterized on the index source.
    auto run_rounds = [&](auto IDX) {
        #pragma unroll
        for (int rnd = 0; rnd < 2; ++rnd) {
            const int r  = rnd * 32 + group;       // xs row / channel offset
            const int ls = lbnd[r] - base;
            const int le = lbnd[r + 1] - base;
            floatx4 acc = {0.f, 0.f, 0.f, 0.f};
            for (int i = ls; i < le; i += 8) {     // divergent: exec-masked
                int i1 = i + 1, i2 = i + 2, i3 = i + 3;
                int i4 = i + 4, i5 = i + 5, i6 = i + 6, i7 = i + 7;
                int p0 = IDX(i);
                int p1 = IDX(i1 < le ? i1 : i);
                int p2 = IDX(i2 < le ? i2 : i);
                int p3 = IDX(i3 < le ? i3 : i);
                int p4 = IDX(i4 < le ? i4 : i);
                int p5 = IDX(i5 < le ? i5 : i);
                int p6 = IDX(i6 < le ? i6 : i);
                int p7 = IDX(i7 < le ? i7 : i);
                h4 g0 = *(const h4*)(pbase + (size_t)p0 * NF);
                h4 g1 = *(const h4*)(pbase + (size_t)p1 * NF);
                h4 g2 = *(const h4*)(pbase + (size_t)p2 * NF);
                h4 g3 = *(const h4*)(pbase + (size_t)p3 * NF);
                h4 g4 = *(const h4*)(pbase + (size_t)p4 * NF);
                h4 g5 = *(const h4*)(pbase + (size_t)p5 * NF);
                h4 g6 = *(const h4*)(pbase + (size_t)p6 * NF);
                h4 g7 = *(const h4*)(pbase + (size_t)p7 * NF);
                acc += h4tof4(g0);
                if (i1 < le) acc += h4tof4(g1);
                if (i2 < le) acc += h4tof4(g2);
                if (i3 < le) acc += h4tof4(g3);
                if (i4 < le) acc += h4tof4(g4);
                if (i5 < le) acc += h4tof4(g5);
                if (i6 < le) acc += h4tof4(g6);
                if (i7 < le) acc += h4tof4(g7);
            }
            short4v xb;
            #pragma unroll
            for (int q = 0; q < 4; ++q) xb[q] = f2b(acc[q]);
            *(short4v*)(&xs[r * XROW + fq * 4]) = xb;
        }
    };

    if (cnt <= CAP) {   // block-uniform; statistically always
        run_rounds([&](int j) { return eidx[j]; });
    } else {
        run_rounds([&](int j) { return edge_path[base + j]; });
    }
    __syncthreads();

    // ---- Phase 2: fused GRU via mfma_f32_16x16x32_bf16 (verified).
    const int quad = lane >> 4;
    const int n16  = lane & 15;
    const int k0   = quad * 8;

    const int rA = w * 16 + n16;
    short8 ax = *(const short8*)(&xs[rA * XROW + k0]);

    const size_t mrow = (size_t)batch * NC + c0;     // block's first row
    const float* hrow = hbuf + (mrow + rA) * NF + k0;
    floatx4 h0 = __builtin_nontemporal_load((const floatx4*)(hrow));
    floatx4 h1 = __builtin_nontemporal_load((const floatx4*)(hrow + 4));
    short8 ah;
    #pragma unroll
    for (int q = 0; q < 4; ++q) { ah[q] = f2b(h0[q]); ah[4 + q] = f2b(h1[q]); }

    float bxv[6], bhv[6];
    #pragma unroll
    for (int tt = 0; tt < 6; ++tt) {
        bxv[tt] = b_ih[16 * tt + n16];
        bhv[tt] = b_hh[16 * tt + n16];
    }

    const floatx4 zero = {0.f, 0.f, 0.f, 0.f};
    // r,z gates: x- and h-MFMAs chain into ONE accumulator. n gate needs
    // xn and hn separate (r gates hn).
    floatx4 g[4];
    #pragma unroll
    for (int tt = 0; tt < 4; ++tt) {
        short8 bw = *(const short8*)(&wsx[(16 * tt + n16) * XROW + k0]);
        floatx4 a = __builtin_amdgcn_mfma_f32_16x16x32_bf16(ax, bw, zero, 0, 0, 0);
        bw = *(const short8*)(&wsh[(16 * tt + n16) * XROW + k0]);
        g[tt] = __builtin_amdgcn_mfma_f32_16x16x32_bf16(ah, bw, a, 0, 0, 0);
    }
    floatx4 nx[2], nh[2];
    #pragma unroll
    for (int u = 0; u < 2; ++u) {
        const int tt = 4 + u;
        short8 bw = *(const short8*)(&wsx[(16 * tt + n16) * XROW + k0]);
        nx[u] = __builtin_amdgcn_mfma_f32_16x16x32_bf16(ax, bw, zero, 0, 0, 0);
        bw = *(const short8*)(&wsh[(16 * tt + n16) * XROW + k0]);
        nh[u] = __builtin_amdgcn_mfma_f32_16x16x32_bf16(ah, bw, zero, 0, 0, 0);
    }

    // Epilogue in C-layout (col = lane&15, row = quad*4+i), fp32 h blend.
    // NT loads/stores: keep the 32MB h/out streams out of the L2 slice.
    #pragma unroll
    for (int i = 0; i < 4; ++i) {
        const int r2 = w * 16 + quad * 4 + i;
        const size_t m = mrow + r2;
        float r0 = sigmoidf_(g[0][i] + bxv[0] + bhv[0]);
        float r1 = sigmoidf_(g[1][i] + bxv[1] + bhv[1]);
        float z0 = sigmoidf_(g[2][i] + bxv[2] + bhv[2]);
        float z1 = sigmoidf_(g[3][i] + bxv[3] + bhv[3]);
        float n0 = tanhf_(nx[0][i] + bxv[4] + r0 * (nh[0][i] + bhv[4]));
        float n1 = tanhf_(nx[1][i] + bxv[5] + r1 * (nh[1][i] + bhv[5]));
        float hv0 = __builtin_nontemporal_load(&hbuf[m * NF + n16]);
        float hv1 = __builtin_nontemporal_load(&hbuf[m * NF + 16 + n16]);
        __builtin_nontemporal_store((1.f - z0) * n0 + z0 * hv0, &out[m * NF + n16]);
        __builtin_nontemporal_store((1.f - z1) * n1 + z1 * hv1, &out[m * NF + 16 + n16]);
    }
}

// ---------------------------------------------------------------------------
// Fallback (ws too small): r11's verified fp32-gather fused kernel,
// 8 channels/block, in-kernel binary search.
// ---------------------------------------------------------------------------
__global__ __launch_bounds__(256) void fused_gru_fb(
    const float*  __restrict__ path,
    const float*  __restrict__ hbuf,
    const float*  __restrict__ W_ih,
    const float*  __restrict__ W_hh,
    const float*  __restrict__ b_ih,
    const float*  __restrict__ b_hh,
    const int*    __restrict__ edge_path,
    const int*    __restrict__ edge_channel,
    float*        __restrict__ out)
{
    const int t    = threadIdx.x;
    const int w    = t >> 6;
    const int lane = t & 63;
    const int cblk = blockIdx.x * 8;

    __shared__ int bounds[9];
    __shared__ __align__(16) short xs [64 * XROW];
    __shared__ __align__(16) short wsx[96 * XROW];
    __shared__ __align__(16) short wsh[96 * XROW];

    if (t < 9) bounds[t] = lower_bound(edge_channel, cblk + t);
    for (int idx = t; idx < 96 * NF; idx += 256) {
        int r = idx >> 5, c = idx & 31;
        wsx[r * XROW + c] = f2b(W_ih[idx]);
        wsh[r * XROW + c] = f2b(W_hh[idx]);
    }
    __syncthreads();

    const int b  = lane >> 3;
    const int fq = lane & 7;
    const float* prow = path + (size_t)b * (NP * NF) + fq * 4;

    #pragma unroll
    for (int half = 0; half < 2; ++half) {
        const int cl = w * 2 + half;
        const int s = __builtin_amdgcn_readfirstlane(bounds[cl]);
        const int e = __builtin_amdgcn_readfirstlane(bounds[cl + 1]);
        floatx4 acc = {0.f, 0.f, 0.f, 0.f};
        int i = s;
        for (; i + 8 <= e; i += 8) {
            int p0 = edge_path[i + 0], p1 = edge_path[i + 1];
            int p2 = edge_path[i + 2], p3 = edge_path[i + 3];
            int p4 = edge_path[i + 4], p5 = edge_path[i + 5];
            int p6 = edge_path[i + 6], p7 = edge_path[i + 7];
            floatx4 g0 = *(const floatx4*)(prow + (size_t)p0 * NF);
            floatx4 g1 = *(const floatx4*)(prow + (size_t)p1 * NF);
            floatx4 g2 = *(const floatx4*)(prow + (size_t)p2 * NF);
            floatx4 g3 = *(const floatx4*)(prow + (size_t)p3 * NF);
            floatx4 g4 = *(const floatx4*)(prow + (size_t)p4 * NF);
            floatx4 g5 = *(const floatx4*)(prow + (size_t)p5 * NF);
            floatx4 g6 = *(const floatx4*)(prow + (size_t)p6 * NF);
            floatx4 g7 = *(const floatx4*)(prow + (size_t)p7 * NF);
            acc += ((g0 + g1) + (g2 + g3)) + ((g4 + g5) + (g6 + g7));
        }
        for (; i < e; ++i)
            acc += *(const floatx4*)(prow + (size_t)edge_path[i] * NF);
        short4v xb;
        #pragma unroll
        for (int q = 0; q < 4; ++q) xb[q] = f2b(acc[q]);
        *(short4v*)(&xs[(b * 8 + cl) * XROW + fq * 4]) = xb;
    }
    __syncthreads();

    const int quad = lane >> 4;
    const int n16  = lane & 15;
    const int k0   = quad * 8;

    const int rA = w * 16 + n16;
    short8 ax = *(const short8*)(&xs[rA * XROW + k0]);
    const int bA = rA >> 3;
    const int cA = cblk + (rA & 7);
    const float* hrow = hbuf + ((size_t)bA * NC + cA) * NF + k0;
    floatx4 h0 = *(const floatx4*)(hrow);
    floatx4 h1 = *(const floatx4*)(hrow + 4);
    short8 ah;
    #pragma unroll
    for (int q = 0; q < 4; ++q) { ah[q] = f2b(h0[q]); ah[4 + q] = f2b(h1[q]); }

    float bxv[6], bhv[6];
    #pragma unroll
    for (int tt = 0; tt < 6; ++tt) {
        bxv[tt] = b_ih[16 * tt + n16];
        bhv[tt] = b_hh[16 * tt + n16];
    }
    const floatx4 zero = {0.f, 0.f, 0.f, 0.f};
    floatx4 g[4];
    #pragma unroll
    for (int tt = 0; tt < 4; ++tt) {
        short8 bw = *(const short8*)(&wsx[(16 * tt + n16) * XROW + k0]);
        floatx4 a = __builtin_amdgcn_mfma_f32_16x16x32_bf16(ax, bw, zero, 0, 0, 0);
        bw = *(const short8*)(&wsh[(16 * tt + n16) * XROW + k0]);
        g[tt] = __builtin_amdgcn_mfma_f32_16x16x32_bf16(ah, bw, a, 0, 0, 0);
    }
    floatx4 nx[2], nh[2];
    #pragma unroll
    for (int u = 0; u < 2; ++u) {
        const int tt = 4 + u;
        short8 bw = *(const short8*)(&wsx[(16 * tt + n16) * XROW + k0]);
        nx[u] = __builtin_amdgcn_mfma_f32_16x16x32_bf16(ax, bw, zero, 0, 0, 0);
        bw = *(const short8*)(&wsh[(16 * tt + n16) * XROW + k0]);
        nh[u] = __builtin_amdgcn_mfma_f32_16x16x32_bf16(ah, bw, zero, 0, 0, 0);
    }
    #pragma unroll
    for (int i = 0; i < 4; ++i) {
        const int r  = w * 16 + quad * 4 + i;
        const int b2 = r >> 3;
        const size_t m = (size_t)b2 * NC + (cblk + (r & 7));
        float r0 = sigmoidf_(g[0][i] + bxv[0] + bhv[0]);
        float r1 = sigmoidf_(g[1][i] + bxv[1] + bhv[1]);
        float z0 = sigmoidf_(g[2][i] + bxv[2] + bhv[2]);
        float z1 = sigmoidf_(g[3][i] + bxv[3] + bhv[3]);
        float n0 = tanhf_(nx[0][i] + bxv[4] + r0 * (nh[0][i] + bhv[4]));
        float n1 = tanhf_(nx[1][i] + bxv[5] + r1 * (nh[1][i] + bhv[5]));
        float hv0 = hbuf[m * NF + n16];
        float hv1 = hbuf[m * NF + 16 + n16];
        out[m * NF + n16]      = (1.f - z0) * n0 + z0 * hv0;
        out[m * NF + 16 + n16] = (1.f - z1) * n1 + z1 * hv1;
    }
}

extern "C" void kernel_launch(void* const* d_in, const int* in_sizes, int n_in,
                              void* d_out, int out_size, void* d_ws, size_t ws_size,
                              hipStream_t stream) {
    const float* path = (const float*)d_in[0];  // [8,65536,32] fp32
    const float* chan = (const float*)d_in[1];  // [8,32768,32] fp32
    const float* W_ih = (const float*)d_in[2];  // [96,32]
    const float* W_hh = (const float*)d_in[3];  // [96,32]
    const float* b_ih = (const float*)d_in[4];  // [96]
    const float* b_hh = (const float*)d_in[5];  // [96]
    const int* edge_path    = (const int*)d_in[6];
    const int* edge_channel = (const int*)d_in[7];
    float* out = (float*)d_out;                 // [8,32768,32] fp32

    const size_t pathH_bytes = (size_t)NB * NP * NF * sizeof(__half);  // 32MB
    const size_t need = pathH_bytes + (size_t)(NC + 1) * sizeof(int);
    if (ws_size >= need) {
        __half* pathH = (__half*)d_ws;
        int* bounds = (int*)((char*)d_ws + pathH_bytes);
        const int bblocks = (NC + 1 + 255) / 256;    // 129
        prep_kernel<<<dim3(CONV_BLOCKS + bblocks), dim3(256), 0, stream>>>(
            path, pathH, edge_channel, bounds);
        fused_gru_new<<<dim3((NC / CHB) * NB), dim3(256), 0, stream>>>(
            pathH, chan, W_ih, W_hh, b_ih, b_hh, edge_path, bounds, out);
    } else {
        fused_gru_fb<<<dim3(NC / 8), dim3(256), 0, stream>>>(
            path, chan, W_ih, W_hh, b_ih, b_hh, edge_path, edge_channel, out);
    }
}

// Round 7
// 210.169 us; speedup vs baseline: 1.4045x; 1.0377x over previous
//
// GRUCell2 MI355X — r15: 16B/lane gather (halve the divergent-address count).
// Evidence chain: r14 FETCH=74.7MB decomposes to path ~1.0x (slice fully
// L2-resident) + h + edges => bytes optimal; HBM 16%, VALU 42%, MFMA 1.5%,
// occupancy 45% => NOTHING saturated, yet r10/r11/r13/r14 all floor at
// 84-94us. Invariant across them: scattered wave64 loads at 8B/lane = 64
// divergent addresses/instr. TA model ~1 addr/lane/cy => 3K gather instrs/CU
// x 64cy ~= 82us — matches the floor. Fix: edge row (64B fp16) loaded by
// 4 lanes x dwordx4 (16B/lane): addresses/edge 8 -> 4. Mapping: lane =
// (eslot:16, fh:4); 64 4-lane groups = 64 channels in ONE round; lane
// accumulates 8 features. All else held fixed from r14 (batch-per-XCD slice,
// LDS indices, LDS weights, MFMA GRU, NT streams) to isolate the variable.
#include <hip/hip_runtime.h>
#include <hip/hip_fp16.h>

#define NB 8
#define NP 65536
#define NC 32768
#define NF 32
#define NE 524288
#define XROW 40   // shorts per LDS row (80B): 16B-aligned b128 reads, 2-way banks max
#define CHB 64    // channels per block: one per 4-lane group, single round
#define CAP 2048  // staged indices per block (mean 1024, +32 sigma)
#define CONV_BLOCKS 8192   // (NB*NP*NF / 8) / 256

typedef __attribute__((ext_vector_type(4))) float floatx4;
typedef __attribute__((ext_vector_type(8))) short short8;
typedef __attribute__((ext_vector_type(4))) short short4v;

struct h4 { __half2 lo, hi; };          // 8B
struct h8 { __half2 a, b, c, d; };      // 16B: one global_load_dwordx4

__device__ __forceinline__ floatx4 h4tof4(h4 v) {
    float2 a = __half22float2(v.lo);
    float2 b = __half22float2(v.hi);
    floatx4 r; r[0] = a.x; r[1] = a.y; r[2] = b.x; r[3] = b.y;
    return r;
}

__device__ __forceinline__ short f2b(float f) {
    union { float f; unsigned int u; } v;
    v.f = f;
    unsigned int lsb = (v.u >> 16) & 1u;
    v.u += 0x7fffu + lsb;   // round-to-nearest-even
    return (short)(v.u >> 16);
}

__device__ __forceinline__ int lower_bound(const int* __restrict__ a, int v) {
    int lo = 0, hi = NE;
    while (lo < hi) {
        int mid = (lo + hi) >> 1;
        if (a[mid] < v) lo = mid + 1; else hi = mid;
    }
    return lo;
}

__device__ __forceinline__ float sigmoidf_(float v) {
    return 1.f / (1.f + __expf(-v));
}
__device__ __forceinline__ float tanhf_(float v) {
    v = fminf(v, 40.f);
    float t = __expf(2.f * v);
    return (t - 1.f) / (t + 1.f);
}

// ---------------------------------------------------------------------------
// Prepass (one kernel, two parts by blockIdx):
//   blocks [0, CONV_BLOCKS): pathH[i] = fp16(path[i])  (NT streaming convert)
//   blocks [CONV_BLOCKS, +129): bounds[c] = lower_bound(edge_channel, c)
// ---------------------------------------------------------------------------
__global__ __launch_bounds__(256) void prep_kernel(
    const float* __restrict__ path, __half* __restrict__ pathH,
    const int* __restrict__ edge_channel, int* __restrict__ bounds)
{
    if (blockIdx.x < CONV_BLOCKS) {
        const size_t id = ((size_t)blockIdx.x * 256 + threadIdx.x) * 8;
        floatx4 v0 = __builtin_nontemporal_load((const floatx4*)(path + id));
        floatx4 v1 = __builtin_nontemporal_load((const floatx4*)(path + id + 4));
        h8 o;
        o.a = __floats2half2_rn(v0[0], v0[1]);
        o.b = __floats2half2_rn(v0[2], v0[3]);
        o.c = __floats2half2_rn(v1[0], v1[1]);
        o.d = __floats2half2_rn(v1[2], v1[3]);
        union { h8 s; floatx4 f; } cv; cv.s = o;
        __builtin_nontemporal_store(cv.f, (floatx4*)(pathH + id));
    } else {
        const int c = (blockIdx.x - CONV_BLOCKS) * 256 + threadIdx.x;
        if (c <= NC) bounds[c] = lower_bound(edge_channel, c);
    }
}

// ---------------------------------------------------------------------------
// Fused gather + GRU, batch-sliced. Block = 1 batch x 64 channels.
// Phase 0: stage the block's contiguous edge-index range into LDS (coalesced).
// Phase 1: 64 groups of 4 lanes; group g owns channel c0+g; lane loads 16B
// (8 features) per edge via dwordx4 -> 4 addresses/edge (was 8); indices from
// LDS (broadcast ds_read); unroll-8 keeps 8KB/wave in flight.
// Phase 2: verified MFMA GRU; NT h loads / out stores protect the L2 slice.
// ---------------------------------------------------------------------------
__global__ __launch_bounds__(256) void fused_gru_new(
    const __half* __restrict__ pathH,        // [B,P,F] fp16 (d_ws)
    const float*  __restrict__ hbuf,         // [B,C,F] fp32
    const float*  __restrict__ W_ih,         // [96,32] fp32
    const float*  __restrict__ W_hh,         // [96,32] fp32
    const float*  __restrict__ b_ih,         // [96]
    const float*  __restrict__ b_hh,         // [96]
    const int*    __restrict__ edge_path,    // [E]
    const int*    __restrict__ bounds,       // [NC+1] (d_ws)
    float*        __restrict__ out)          // [B,C,F] fp32
{
    const int t    = threadIdx.x;
    const int w    = t >> 6;      // wave 0..3
    const int lane = t & 63;
    const int batch = blockIdx.x & 7;            // == XCD id under %8 dispatch
    const int c0    = (blockIdx.x >> 3) * CHB;

    __shared__ __align__(16) short xs [64 * XROW];   // x rows bf16, r = c - c0
    __shared__ __align__(16) short wsx[96 * XROW];   // W_ih bf16
    __shared__ __align__(16) short wsh[96 * XROW];   // W_hh bf16
    __shared__ int lbnd[CHB + 1];
    __shared__ int eidx[CAP];

    // Stage weights -> LDS bf16 once per block (24KB, L2-hot).
    for (int idx = t; idx < 96 * NF; idx += 256) {
        int r = idx >> 5, c = idx & 31;
        wsx[r * XROW + c] = f2b(W_ih[idx]);
        wsh[r * XROW + c] = f2b(W_hh[idx]);
    }
    if (t <= CHB) lbnd[t] = bounds[c0 + t];

    // Stage this block's contiguous edge-index range (coalesced).
    const int base = bounds[c0];                   // broadcast load
    const int cnt  = bounds[c0 + CHB] - base;
    const int cntc = cnt < CAP ? cnt : CAP;
    for (int j = t; j < cntc; j += 256) eidx[j] = edge_path[base + j];
    __syncthreads();

    // ---- Phase 1: gather from this batch's 4MB L2-resident slice.
    const int g  = t >> 2;           // 0..63: channel group (4 lanes)
    const int fh = t & 3;            // feature half-quad: halves fh*8..fh*8+7
    const __half* pbase = pathH + (size_t)batch * (NP * NF) + fh * 8;

    const int ls = lbnd[g];
    const int le = lbnd[g + 1];
    floatx4 accL = {0.f, 0.f, 0.f, 0.f};
    floatx4 accH = {0.f, 0.f, 0.f, 0.f};

    auto run_gather = [&](auto IDX) {
        for (int i = ls; i < le; i += 8) {       // divergent: exec-masked
            int i1 = i + 1, i2 = i + 2, i3 = i + 3;
            int i4 = i + 4, i5 = i + 5, i6 = i + 6, i7 = i + 7;
            int p0 = IDX(i);
            int p1 = IDX(i1 < le ? i1 : i);
            int p2 = IDX(i2 < le ? i2 : i);
            int p3 = IDX(i3 < le ? i3 : i);
            int p4 = IDX(i4 < le ? i4 : i);
            int p5 = IDX(i5 < le ? i5 : i);
            int p6 = IDX(i6 < le ? i6 : i);
            int p7 = IDX(i7 < le ? i7 : i);
            h8 g0 = *(const h8*)(pbase + (size_t)p0 * NF);
            h8 g1 = *(const h8*)(pbase + (size_t)p1 * NF);
            h8 g2 = *(const h8*)(pbase + (size_t)p2 * NF);
            h8 g3 = *(const h8*)(pbase + (size_t)p3 * NF);
            h8 g4 = *(const h8*)(pbase + (size_t)p4 * NF);
            h8 g5 = *(const h8*)(pbase + (size_t)p5 * NF);
            h8 g6 = *(const h8*)(pbase + (size_t)p6 * NF);
            h8 g7 = *(const h8*)(pbase + (size_t)p7 * NF);
            h4 a0; a0.lo = g0.a; a0.hi = g0.b;  h4 b0; b0.lo = g0.c; b0.hi = g0.d;
            accL += h4tof4(a0); accH += h4tof4(b0);
            if (i1 < le) { h4 a; a.lo = g1.a; a.hi = g1.b; h4 b; b.lo = g1.c; b.hi = g1.d;
                           accL += h4tof4(a); accH += h4tof4(b); }
            if (i2 < le) { h4 a; a.lo = g2.a; a.hi = g2.b; h4 b; b.lo = g2.c; b.hi = g2.d;
                           accL += h4tof4(a); accH += h4tof4(b); }
            if (i3 < le) { h4 a; a.lo = g3.a; a.hi = g3.b; h4 b; b.lo = g3.c; b.hi = g3.d;
                           accL += h4tof4(a); accH += h4tof4(b); }
            if (i4 < le) { h4 a; a.lo = g4.a; a.hi = g4.b; h4 b; b.lo = g4.c; b.hi = g4.d;
                           accL += h4tof4(a); accH += h4tof4(b); }
            if (i5 < le) { h4 a; a.lo = g5.a; a.hi = g5.b; h4 b; b.lo = g5.c; b.hi = g5.d;
                           accL += h4tof4(a); accH += h4tof4(b); }
            if (i6 < le) { h4 a; a.lo = g6.a; a.hi = g6.b; h4 b; b.lo = g6.c; b.hi = g6.d;
                           accL += h4tof4(a); accH += h4tof4(b); }
            if (i7 < le) { h4 a; a.lo = g7.a; a.hi = g7.b; h4 b; b.lo = g7.c; b.hi = g7.d;
                           accL += h4tof4(a); accH += h4tof4(b); }
        }
    };

    if (cnt <= CAP) {   // block-uniform; statistically always
        run_gather([&](int j) { return eidx[j - base]; });
    } else {
        run_gather([&](int j) { return edge_path[j]; });
    }

    {
        short8 xb;
        #pragma unroll
        for (int q = 0; q < 4; ++q) { xb[q] = f2b(accL[q]); xb[4 + q] = f2b(accH[q]); }
        *(short8*)(&xs[g * XROW + fh * 8]) = xb;
    }
    __syncthreads();

    // ---- Phase 2: fused GRU via mfma_f32_16x16x32_bf16 (verified).
    const int quad = lane >> 4;
    const int n16  = lane & 15;
    const int k0   = quad * 8;

    const int rA = w * 16 + n16;
    short8 ax = *(const short8*)(&xs[rA * XROW + k0]);

    const size_t mrow = (size_t)batch * NC + c0;     // block's first row
    const float* hrow = hbuf + (mrow + rA) * NF + k0;
    floatx4 h0 = __builtin_nontemporal_load((const floatx4*)(hrow));
    floatx4 h1 = __builtin_nontemporal_load((const floatx4*)(hrow + 4));
    short8 ah;
    #pragma unroll
    for (int q = 0; q < 4; ++q) { ah[q] = f2b(h0[q]); ah[4 + q] = f2b(h1[q]); }

    float bxv[6], bhv[6];
    #pragma unroll
    for (int tt = 0; tt < 6; ++tt) {
        bxv[tt] = b_ih[16 * tt + n16];
        bhv[tt] = b_hh[16 * tt + n16];
    }

    const floatx4 zero = {0.f, 0.f, 0.f, 0.f};
    // r,z gates: x- and h-MFMAs chain into ONE accumulator. n gate needs
    // xn and hn separate (r gates hn).
    floatx4 gg[4];
    #pragma unroll
    for (int tt = 0; tt < 4; ++tt) {
        short8 bw = *(const short8*)(&wsx[(16 * tt + n16) * XROW + k0]);
        floatx4 a = __builtin_amdgcn_mfma_f32_16x16x32_bf16(ax, bw, zero, 0, 0, 0);
        bw = *(const short8*)(&wsh[(16 * tt + n16) * XROW + k0]);
        gg[tt] = __builtin_amdgcn_mfma_f32_16x16x32_bf16(ah, bw, a, 0, 0, 0);
    }
    floatx4 nx[2], nh[2];
    #pragma unroll
    for (int u = 0; u < 2; ++u) {
        const int tt = 4 + u;
        short8 bw = *(const short8*)(&wsx[(16 * tt + n16) * XROW + k0]);
        nx[u] = __builtin_amdgcn_mfma_f32_16x16x32_bf16(ax, bw, zero, 0, 0, 0);
        bw = *(const short8*)(&wsh[(16 * tt + n16) * XROW + k0]);
        nh[u] = __builtin_amdgcn_mfma_f32_16x16x32_bf16(ah, bw, zero, 0, 0, 0);
    }

    // Epilogue in C-layout (col = lane&15, row = quad*4+i), fp32 h blend.
    // NT loads/stores: keep the 32MB h/out streams out of the L2 slice.
    #pragma unroll
    for (int i = 0; i < 4; ++i) {
        const int r2 = w * 16 + quad * 4 + i;
        const size_t m = mrow + r2;
        float r0 = sigmoidf_(gg[0][i] + bxv[0] + bhv[0]);
        float r1 = sigmoidf_(gg[1][i] + bxv[1] + bhv[1]);
        float z0 = sigmoidf_(gg[2][i] + bxv[2] + bhv[2]);
        float z1 = sigmoidf_(gg[3][i] + bxv[3] + bhv[3]);
        float n0 = tanhf_(nx[0][i] + bxv[4] + r0 * (nh[0][i] + bhv[4]));
        float n1 = tanhf_(nx[1][i] + bxv[5] + r1 * (nh[1][i] + bhv[5]));
        float hv0 = __builtin_nontemporal_load(&hbuf[m * NF + n16]);
        float hv1 = __builtin_nontemporal_load(&hbuf[m * NF + 16 + n16]);
        __builtin_nontemporal_store((1.f - z0) * n0 + z0 * hv0, &out[m * NF + n16]);
        __builtin_nontemporal_store((1.f - z1) * n1 + z1 * hv1, &out[m * NF + 16 + n16]);
    }
}

// ---------------------------------------------------------------------------
// Fallback (ws too small): r11's verified fp32-gather fused kernel,
// 8 channels/block, in-kernel binary search.
// ---------------------------------------------------------------------------
__global__ __launch_bounds__(256) void fused_gru_fb(
    const float*  __restrict__ path,
    const float*  __restrict__ hbuf,
    const float*  __restrict__ W_ih,
    const float*  __restrict__ W_hh,
    const float*  __restrict__ b_ih,
    const float*  __restrict__ b_hh,
    const int*    __restrict__ edge_path,
    const int*    __restrict__ edge_channel,
    float*        __restrict__ out)
{
    const int t    = threadIdx.x;
    const int w    = t >> 6;
    const int lane = t & 63;
    const int cblk = blockIdx.x * 8;

    __shared__ int bounds[9];
    __shared__ __align__(16) short xs [64 * XROW];
    __shared__ __align__(16) short wsx[96 * XROW];
    __shared__ __align__(16) short wsh[96 * XROW];

    if (t < 9) bounds[t] = lower_bound(edge_channel, cblk + t);
    for (int idx = t; idx < 96 * NF; idx += 256) {
        int r = idx >> 5, c = idx & 31;
        wsx[r * XROW + c] = f2b(W_ih[idx]);
        wsh[r * XROW + c] = f2b(W_hh[idx]);
    }
    __syncthreads();

    const int b  = lane >> 3;
    const int fq = lane & 7;
    const float* prow = path + (size_t)b * (NP * NF) + fq * 4;

    #pragma unroll
    for (int half = 0; half < 2; ++half) {
        const int cl = w * 2 + half;
        const int s = __builtin_amdgcn_readfirstlane(bounds[cl]);
        const int e = __builtin_amdgcn_readfirstlane(bounds[cl + 1]);
        floatx4 acc = {0.f, 0.f, 0.f, 0.f};
        int i = s;
        for (; i + 8 <= e; i += 8) {
            int p0 = edge_path[i + 0], p1 = edge_path[i + 1];
            int p2 = edge_path[i + 2], p3 = edge_path[i + 3];
            int p4 = edge_path[i + 4], p5 = edge_path[i + 5];
            int p6 = edge_path[i + 6], p7 = edge_path[i + 7];
            floatx4 g0 = *(const floatx4*)(prow + (size_t)p0 * NF);
            floatx4 g1 = *(const floatx4*)(prow + (size_t)p1 * NF);
            floatx4 g2 = *(const floatx4*)(prow + (size_t)p2 * NF);
            floatx4 g3 = *(const floatx4*)(prow + (size_t)p3 * NF);
            floatx4 g4 = *(const floatx4*)(prow + (size_t)p4 * NF);
            floatx4 g5 = *(const floatx4*)(prow + (size_t)p5 * NF);
            floatx4 g6 = *(const floatx4*)(prow + (size_t)p6 * NF);
            floatx4 g7 = *(const floatx4*)(prow + (size_t)p7 * NF);
            acc += ((g0 + g1) + (g2 + g3)) + ((g4 + g5) + (g6 + g7));
        }
        for (; i < e; ++i)
            acc += *(const floatx4*)(prow + (size_t)edge_path[i] * NF);
        short4v xb;
        #pragma unroll
        for (int q = 0; q < 4; ++q) xb[q] = f2b(acc[q]);
        *(short4v*)(&xs[(b * 8 + cl) * XROW + fq * 4]) = xb;
    }
    __syncthreads();

    const int quad = lane >> 4;
    const int n16  = lane & 15;
    const int k0   = quad * 8;

    const int rA = w * 16 + n16;
    short8 ax = *(const short8*)(&xs[rA * XROW + k0]);
    const int bA = rA >> 3;
    const int cA = cblk + (rA & 7);
    const float* hrow = hbuf + ((size_t)bA * NC + cA) * NF + k0;
    floatx4 h0 = *(const floatx4*)(hrow);
    floatx4 h1 = *(const floatx4*)(hrow + 4);
    short8 ah;
    #pragma unroll
    for (int q = 0; q < 4; ++q) { ah[q] = f2b(h0[q]); ah[4 + q] = f2b(h1[q]); }

    float bxv[6], bhv[6];
    #pragma unroll
    for (int tt = 0; tt < 6; ++tt) {
        bxv[tt] = b_ih[16 * tt + n16];
        bhv[tt] = b_hh[16 * tt + n16];
    }
    const floatx4 zero = {0.f, 0.f, 0.f, 0.f};
    floatx4 g[4];
    #pragma unroll
    for (int tt = 0; tt < 4; ++tt) {
        short8 bw = *(const short8*)(&wsx[(16 * tt + n16) * XROW + k0]);
        floatx4 a = __builtin_amdgcn_mfma_f32_16x16x32_bf16(ax, bw, zero, 0, 0, 0);
        bw = *(const short8*)(&wsh[(16 * tt + n16) * XROW + k0]);
        g[tt] = __builtin_amdgcn_mfma_f32_16x16x32_bf16(ah, bw, a, 0, 0, 0);
    }
    floatx4 nx[2], nh[2];
    #pragma unroll
    for (int u = 0; u < 2; ++u) {
        const int tt = 4 + u;
        short8 bw = *(const short8*)(&wsx[(16 * tt + n16) * XROW + k0]);
        nx[u] = __builtin_amdgcn_mfma_f32_16x16x32_bf16(ax, bw, zero, 0, 0, 0);
        bw = *(const short8*)(&wsh[(16 * tt + n16) * XROW + k0]);
        nh[u] = __builtin_amdgcn_mfma_f32_16x16x32_bf16(ah, bw, zero, 0, 0, 0);
    }
    #pragma unroll
    for (int i = 0; i < 4; ++i) {
        const int r  = w * 16 + quad * 4 + i;
        const int b2 = r >> 3;
        const size_t m = (size_t)b2 * NC + (cblk + (r & 7));
        float r0 = sigmoidf_(g[0][i] + bxv[0] + bhv[0]);
        float r1 = sigmoidf_(g[1][i] + bxv[1] + bhv[1]);
        float z0 = sigmoidf_(g[2][i] + bxv[2] + bhv[2]);
        float z1 = sigmoidf_(g[3][i] + bxv[3] + bhv[3]);
        float n0 = tanhf_(nx[0][i] + bxv[4] + r0 * (nh[0][i] + bhv[4]));
        float n1 = tanhf_(nx[1][i] + bxv[5] + r1 * (nh[1][i] + bhv[5]));
        float hv0 = hbuf[m * NF + n16];
        float hv1 = hbuf[m * NF + 16 + n16];
        out[m * NF + n16]      = (1.f - z0) * n0 + z0 * hv0;
        out[m * NF + 16 + n16] = (1.f - z1) * n1 + z1 * hv1;
    }
}

extern "C" void kernel_launch(void* const* d_in, const int* in_sizes, int n_in,
                              void* d_out, int out_size, void* d_ws, size_t ws_size,
                              hipStream_t stream) {
    const float* path = (const float*)d_in[0];  // [8,65536,32] fp32
    const float* chan = (const float*)d_in[1];  // [8,32768,32] fp32
    const float* W_ih = (const float*)d_in[2];  // [96,32]
    const float* W_hh = (const float*)d_in[3];  // [96,32]
    const float* b_ih = (const float*)d_in[4];  // [96]
    const float* b_hh = (const float*)d_in[5];  // [96]
    const int* edge_path    = (const int*)d_in[6];
    const int* edge_channel = (const int*)d_in[7];
    float* out = (float*)d_out;                 // [8,32768,32] fp32

    const size_t pathH_bytes = (size_t)NB * NP * NF * sizeof(__half);  // 32MB
    const size_t need = pathH_bytes + (size_t)(NC + 1) * sizeof(int);
    if (ws_size >= need) {
        __half* pathH = (__half*)d_ws;
        int* bounds = (int*)((char*)d_ws + pathH_bytes);
        const int bblocks = (NC + 1 + 255) / 256;    // 129
        prep_kernel<<<dim3(CONV_BLOCKS + bblocks), dim3(256), 0, stream>>>(
            path, pathH, edge_channel, bounds);
        fused_gru_new<<<dim3((NC / CHB) * NB), dim3(256), 0, stream>>>(
            pathH, chan, W_ih, W_hh, b_ih, b_hh, edge_path, bounds, out);
    } else {
        fused_gru_fb<<<dim3(NC / 8), dim3(256), 0, stream>>>(
            path, chan, W_ih, W_hh, b_ih, b_hh, edge_path, edge_channel, out);
    }
}

// Round 8
// 194.842 us; speedup vs baseline: 1.5149x; 1.0787x over previous
//
// GRUCell2 MI355X — r16: occupancy release (512-thr blocks, ushort LDS
// indices, prep-converted bf16 weights). r15 post-mortem: addr-halving gave
// only -8% => TA-address model wrong. Counters show NOTHING saturated (VALU
// 41%, HBM 18%, L2 ~10%) at Occupancy 45% => latency-bound, short on resident
// waves. Cause: 29.2KB LDS -> 5 blocks x 4 waves = 20 waves/CU cap. Fix:
// (a) 512-thread blocks CHB=128: 8 waves share one weight/LDS copy;
// (b) eidx ushort (edge_path < 65536 exactly): 8KB at CAP=4096 (+45 sigma);
// (c) weights pre-converted to bf16 in prep (12KB d_ws): staging = pure
//     short8 copy, no f2b, no W fp32 refetch.
// LDS 34.3KB/8-wave block -> 4 blocks/CU = 32 waves = 100% cap (was 62.5%).
// Gather microstructure held fixed (4-lane groups, 16B/lane, unroll-8,
// LDS indices, batch-per-XCD slice, NT streams).
#include <hip/hip_runtime.h>
#include <hip/hip_fp16.h>

#define NB 8
#define NP 65536
#define NC 32768
#define NF 32
#define NE 524288
#define XROW 40    // shorts per LDS row (80B): 16B-aligned b128 reads, 2-way banks max
#define CHB 128    // channels per block: one per 4-lane group, 512 threads
#define CAP 4096   // staged ushort indices per block (mean 2048, +45 sigma)
#define CONV_BLOCKS 8192   // (NB*NP*NF / 8) / 256

typedef __attribute__((ext_vector_type(4))) float floatx4;
typedef __attribute__((ext_vector_type(8))) short short8;
typedef __attribute__((ext_vector_type(4))) short short4v;

struct h4 { __half2 lo, hi; };          // 8B
struct h8 { __half2 a, b, c, d; };      // 16B: one global_load_dwordx4

__device__ __forceinline__ floatx4 h4tof4(h4 v) {
    float2 a = __half22float2(v.lo);
    float2 b = __half22float2(v.hi);
    floatx4 r; r[0] = a.x; r[1] = a.y; r[2] = b.x; r[3] = b.y;
    return r;
}

__device__ __forceinline__ short f2b(float f) {
    union { float f; unsigned int u; } v;
    v.f = f;
    unsigned int lsb = (v.u >> 16) & 1u;
    v.u += 0x7fffu + lsb;   // round-to-nearest-even
    return (short)(v.u >> 16);
}

__device__ __forceinline__ int lower_bound(const int* __restrict__ a, int v) {
    int lo = 0, hi = NE;
    while (lo < hi) {
        int mid = (lo + hi) >> 1;
        if (a[mid] < v) lo = mid + 1; else hi = mid;
    }
    return lo;
}

__device__ __forceinline__ float sigmoidf_(float v) {
    return 1.f / (1.f + __expf(-v));
}
__device__ __forceinline__ float tanhf_(float v) {
    v = fminf(v, 40.f);
    float t = __expf(2.f * v);
    return (t - 1.f) / (t + 1.f);
}

// ---------------------------------------------------------------------------
// Prepass (one kernel, three parts by blockIdx):
//   [0, CONV_BLOCKS):      pathH[i] = fp16(path[i])   (NT streaming convert)
//   [CONV_BLOCKS, +129):   bounds[c] = lower_bound(edge_channel, c)
//   [CONV_BLOCKS+129]:     wb = bf16(W_ih) ++ bf16(W_hh)  (12KB)
// ---------------------------------------------------------------------------
__global__ __launch_bounds__(256) void prep_kernel(
    const float* __restrict__ path, __half* __restrict__ pathH,
    const int* __restrict__ edge_channel, int* __restrict__ bounds,
    const float* __restrict__ W_ih, const float* __restrict__ W_hh,
    unsigned short* __restrict__ wb)
{
    const int bblocks = (NC + 1 + 255) / 256;    // 129
    if (blockIdx.x < CONV_BLOCKS) {
        const size_t id = ((size_t)blockIdx.x * 256 + threadIdx.x) * 8;
        floatx4 v0 = __builtin_nontemporal_load((const floatx4*)(path + id));
        floatx4 v1 = __builtin_nontemporal_load((const floatx4*)(path + id + 4));
        h8 o;
        o.a = __floats2half2_rn(v0[0], v0[1]);
        o.b = __floats2half2_rn(v0[2], v0[3]);
        o.c = __floats2half2_rn(v1[0], v1[1]);
        o.d = __floats2half2_rn(v1[2], v1[3]);
        union { h8 s; floatx4 f; } cv; cv.s = o;
        __builtin_nontemporal_store(cv.f, (floatx4*)(pathH + id));
    } else if (blockIdx.x < CONV_BLOCKS + bblocks) {
        const int c = (blockIdx.x - CONV_BLOCKS) * 256 + threadIdx.x;
        if (c <= NC) bounds[c] = lower_bound(edge_channel, c);
    } else {
        for (int j = threadIdx.x; j < 96 * NF; j += 256) {
            wb[j]           = (unsigned short)f2b(W_ih[j]);
            wb[96 * NF + j] = (unsigned short)f2b(W_hh[j]);
        }
    }
}

// ---------------------------------------------------------------------------
// Fused gather + GRU, batch-sliced. Block = 1 batch x 128 channels, 8 waves.
// Phase 0: stage bf16 weights (pure copy from wb), bounds, and the block's
// contiguous ushort edge-index range into LDS (coalesced).
// Phase 1: 128 groups of 4 lanes; group g owns channel c0+g; lane loads 16B
// (8 features) per edge via dwordx4; indices from LDS; unroll-8 in flight.
// Phase 2: verified MFMA GRU; NT h loads / out stores protect the L2 slice.
// ---------------------------------------------------------------------------
__global__ __launch_bounds__(512) void fused_gru_new(
    const __half* __restrict__ pathH,        // [B,P,F] fp16 (d_ws)
    const float*  __restrict__ hbuf,         // [B,C,F] fp32
    const unsigned short* __restrict__ wb,   // [2][96][32] bf16 (d_ws)
    const float*  __restrict__ b_ih,         // [96]
    const float*  __restrict__ b_hh,         // [96]
    const int*    __restrict__ edge_path,    // [E]
    const int*    __restrict__ bounds,       // [NC+1] (d_ws)
    float*        __restrict__ out)          // [B,C,F] fp32
{
    const int t    = threadIdx.x;
    const int w    = t >> 6;      // wave 0..7
    const int lane = t & 63;
    const int batch = blockIdx.x & 7;            // == XCD id under %8 dispatch
    const int c0    = (blockIdx.x >> 3) * CHB;

    __shared__ __align__(16) short xs [CHB * XROW];  // x rows bf16, r = c - c0
    __shared__ __align__(16) short wsx[96 * XROW];   // W_ih bf16
    __shared__ __align__(16) short wsh[96 * XROW];   // W_hh bf16
    __shared__ int lbnd[CHB + 1];
    __shared__ unsigned short eidx[CAP];

    // Stage pre-converted bf16 weights -> LDS (pure short8 copy, 384 threads).
    {
        const int j = t;                     // 96*32/8 = 384 chunks
        if (j < 384) {
            const int r = j >> 2, c = (j & 3) * 8;
            *(short8*)(&wsx[r * XROW + c]) = *(const short8*)(&wb[r * NF + c]);
            *(short8*)(&wsh[r * XROW + c]) = *(const short8*)(&wb[96 * NF + r * NF + c]);
        }
    }
    if (t <= CHB) lbnd[t] = bounds[c0 + t];

    // Stage this block's contiguous edge-index range (coalesced, ushort).
    const int base = bounds[c0];                   // broadcast load
    const int cnt  = bounds[c0 + CHB] - base;
    const int cntc = cnt < CAP ? cnt : CAP;
    for (int j = t; j < cntc; j += 512)
        eidx[j] = (unsigned short)edge_path[base + j];
    __syncthreads();

    // ---- Phase 1: gather from this batch's 4MB L2-resident slice.
    const int g  = t >> 2;           // 0..127: channel group (4 lanes)
    const int fh = t & 3;            // feature half: features fh*8..fh*8+7
    const __half* pbase = pathH + (size_t)batch * (NP * NF) + fh * 8;

    const int ls = lbnd[g];
    const int le = lbnd[g + 1];
    floatx4 accL = {0.f, 0.f, 0.f, 0.f};
    floatx4 accH = {0.f, 0.f, 0.f, 0.f};

    auto run_gather = [&](auto IDX) {
        for (int i = ls; i < le; i += 8) {       // divergent: exec-masked
            int i1 = i + 1, i2 = i + 2, i3 = i + 3;
            int i4 = i + 4, i5 = i + 5, i6 = i + 6, i7 = i + 7;
            int p0 = IDX(i);
            int p1 = IDX(i1 < le ? i1 : i);
            int p2 = IDX(i2 < le ? i2 : i);
            int p3 = IDX(i3 < le ? i3 : i);
            int p4 = IDX(i4 < le ? i4 : i);
            int p5 = IDX(i5 < le ? i5 : i);
            int p6 = IDX(i6 < le ? i6 : i);
            int p7 = IDX(i7 < le ? i7 : i);
            h8 g0 = *(const h8*)(pbase + (size_t)p0 * NF);
            h8 g1 = *(const h8*)(pbase + (size_t)p1 * NF);
            h8 g2 = *(const h8*)(pbase + (size_t)p2 * NF);
            h8 g3 = *(const h8*)(pbase + (size_t)p3 * NF);
            h8 g4 = *(const h8*)(pbase + (size_t)p4 * NF);
            h8 g5 = *(const h8*)(pbase + (size_t)p5 * NF);
            h8 g6 = *(const h8*)(pbase + (size_t)p6 * NF);
            h8 g7 = *(const h8*)(pbase + (size_t)p7 * NF);
            h4 a0; a0.lo = g0.a; a0.hi = g0.b;  h4 b0; b0.lo = g0.c; b0.hi = g0.d;
            accL += h4tof4(a0); accH += h4tof4(b0);
            if (i1 < le) { h4 a; a.lo = g1.a; a.hi = g1.b; h4 b; b.lo = g1.c; b.hi = g1.d;
                           accL += h4tof4(a); accH += h4tof4(b); }
            if (i2 < le) { h4 a; a.lo = g2.a; a.hi = g2.b; h4 b; b.lo = g2.c; b.hi = g2.d;
                           accL += h4tof4(a); accH += h4tof4(b); }
            if (i3 < le) { h4 a; a.lo = g3.a; a.hi = g3.b; h4 b; b.lo = g3.c; b.hi = g3.d;
                           accL += h4tof4(a); accH += h4tof4(b); }
            if (i4 < le) { h4 a; a.lo = g4.a; a.hi = g4.b; h4 b; b.lo = g4.c; b.hi = g4.d;
                           accL += h4tof4(a); accH += h4tof4(b); }
            if (i5 < le) { h4 a; a.lo = g5.a; a.hi = g5.b; h4 b; b.lo = g5.c; b.hi = g5.d;
                           accL += h4tof4(a); accH += h4tof4(b); }
            if (i6 < le) { h4 a; a.lo = g6.a; a.hi = g6.b; h4 b; b.lo = g6.c; b.hi = g6.d;
                           accL += h4tof4(a); accH += h4tof4(b); }
            if (i7 < le) { h4 a; a.lo = g7.a; a.hi = g7.b; h4 b; b.lo = g7.c; b.hi = g7.d;
                           accL += h4tof4(a); accH += h4tof4(b); }
        }
    };

    if (cnt <= CAP) {   // block-uniform; statistically always
        run_gather([&](int j) { return (int)eidx[j - base]; });
    } else {
        run_gather([&](int j) { return edge_path[j]; });
    }

    {
        short8 xb;
        #pragma unroll
        for (int q = 0; q < 4; ++q) { xb[q] = f2b(accL[q]); xb[4 + q] = f2b(accH[q]); }
        *(short8*)(&xs[g * XROW + fh * 8]) = xb;
    }
    __syncthreads();

    // ---- Phase 2: fused GRU via mfma_f32_16x16x32_bf16 (verified).
    const int quad = lane >> 4;
    const int n16  = lane & 15;
    const int k0   = quad * 8;

    const int rA = w * 16 + n16;             // 0..127
    short8 ax = *(const short8*)(&xs[rA * XROW + k0]);

    const size_t mrow = (size_t)batch * NC + c0;     // block's first row
    const float* hrow = hbuf + (mrow + rA) * NF + k0;
    floatx4 h0 = __builtin_nontemporal_load((const floatx4*)(hrow));
    floatx4 h1 = __builtin_nontemporal_load((const floatx4*)(hrow + 4));
    short8 ah;
    #pragma unroll
    for (int q = 0; q < 4; ++q) { ah[q] = f2b(h0[q]); ah[4 + q] = f2b(h1[q]); }

    float bxv[6], bhv[6];
    #pragma unroll
    for (int tt = 0; tt < 6; ++tt) {
        bxv[tt] = b_ih[16 * tt + n16];
        bhv[tt] = b_hh[16 * tt + n16];
    }

    const floatx4 zero = {0.f, 0.f, 0.f, 0.f};
    // r,z gates: x- and h-MFMAs chain into ONE accumulator. n gate needs
    // xn and hn separate (r gates hn).
    floatx4 gg[4];
    #pragma unroll
    for (int tt = 0; tt < 4; ++tt) {
        short8 bw = *(const short8*)(&wsx[(16 * tt + n16) * XROW + k0]);
        floatx4 a = __builtin_amdgcn_mfma_f32_16x16x32_bf16(ax, bw, zero, 0, 0, 0);
        bw = *(const short8*)(&wsh[(16 * tt + n16) * XROW + k0]);
        gg[tt] = __builtin_amdgcn_mfma_f32_16x16x32_bf16(ah, bw, a, 0, 0, 0);
    }
    floatx4 nx[2], nh[2];
    #pragma unroll
    for (int u = 0; u < 2; ++u) {
        const int tt = 4 + u;
        short8 bw = *(const short8*)(&wsx[(16 * tt + n16) * XROW + k0]);
        nx[u] = __builtin_amdgcn_mfma_f32_16x16x32_bf16(ax, bw, zero, 0, 0, 0);
        bw = *(const short8*)(&wsh[(16 * tt + n16) * XROW + k0]);
        nh[u] = __builtin_amdgcn_mfma_f32_16x16x32_bf16(ah, bw, zero, 0, 0, 0);
    }

    // Epilogue in C-layout (col = lane&15, row = quad*4+i), fp32 h blend.
    // NT loads/stores: keep the 32MB h/out streams out of the L2 slice.
    #pragma unroll
    for (int i = 0; i < 4; ++i) {
        const int r2 = w * 16 + quad * 4 + i;
        const size_t m = mrow + r2;
        float r0 = sigmoidf_(gg[0][i] + bxv[0] + bhv[0]);
        float r1 = sigmoidf_(gg[1][i] + bxv[1] + bhv[1]);
        float z0 = sigmoidf_(gg[2][i] + bxv[2] + bhv[2]);
        float z1 = sigmoidf_(gg[3][i] + bxv[3] + bhv[3]);
        float n0 = tanhf_(nx[0][i] + bxv[4] + r0 * (nh[0][i] + bhv[4]));
        float n1 = tanhf_(nx[1][i] + bxv[5] + r1 * (nh[1][i] + bhv[5]));
        float hv0 = __builtin_nontemporal_load(&hbuf[m * NF + n16]);
        float hv1 = __builtin_nontemporal_load(&hbuf[m * NF + 16 + n16]);
        __builtin_nontemporal_store((1.f - z0) * n0 + z0 * hv0, &out[m * NF + n16]);
        __builtin_nontemporal_store((1.f - z1) * n1 + z1 * hv1, &out[m * NF + 16 + n16]);
    }
}

// ---------------------------------------------------------------------------
// Fallback (ws too small): r11's verified fp32-gather fused kernel,
// 8 channels/block, in-kernel binary search.
// ---------------------------------------------------------------------------
__global__ __launch_bounds__(256) void fused_gru_fb(
    const float*  __restrict__ path,
    const float*  __restrict__ hbuf,
    const float*  __restrict__ W_ih,
    const float*  __restrict__ W_hh,
    const float*  __restrict__ b_ih,
    const float*  __restrict__ b_hh,
    const int*    __restrict__ edge_path,
    const int*    __restrict__ edge_channel,
    float*        __restrict__ out)
{
    const int t    = threadIdx.x;
    const int w    = t >> 6;
    const int lane = t & 63;
    const int cblk = blockIdx.x * 8;

    __shared__ int bounds[9];
    __shared__ __align__(16) short xs [64 * XROW];
    __shared__ __align__(16) short wsx[96 * XROW];
    __shared__ __align__(16) short wsh[96 * XROW];

    if (t < 9) bounds[t] = lower_bound(edge_channel, cblk + t);
    for (int idx = t; idx < 96 * NF; idx += 256) {
        int r = idx >> 5, c = idx & 31;
        wsx[r * XROW + c] = f2b(W_ih[idx]);
        wsh[r * XROW + c] = f2b(W_hh[idx]);
    }
    __syncthreads();

    const int b  = lane >> 3;
    const int fq = lane & 7;
    const float* prow = path + (size_t)b * (NP * NF) + fq * 4;

    #pragma unroll
    for (int half = 0; half < 2; ++half) {
        const int cl = w * 2 + half;
        const int s = __builtin_amdgcn_readfirstlane(bounds[cl]);
        const int e = __builtin_amdgcn_readfirstlane(bounds[cl + 1]);
        floatx4 acc = {0.f, 0.f, 0.f, 0.f};
        int i = s;
        for (; i + 8 <= e; i += 8) {
            int p0 = edge_path[i + 0], p1 = edge_path[i + 1];
            int p2 = edge_path[i + 2], p3 = edge_path[i + 3];
            int p4 = edge_path[i + 4], p5 = edge_path[i + 5];
            int p6 = edge_path[i + 6], p7 = edge_path[i + 7];
            floatx4 g0 = *(const floatx4*)(prow + (size_t)p0 * NF);
            floatx4 g1 = *(const floatx4*)(prow + (size_t)p1 * NF);
            floatx4 g2 = *(const floatx4*)(prow + (size_t)p2 * NF);
            floatx4 g3 = *(const floatx4*)(prow + (size_t)p3 * NF);
            floatx4 g4 = *(const floatx4*)(prow + (size_t)p4 * NF);
            floatx4 g5 = *(const floatx4*)(prow + (size_t)p5 * NF);
            floatx4 g6 = *(const floatx4*)(prow + (size_t)p6 * NF);
            floatx4 g7 = *(const floatx4*)(prow + (size_t)p7 * NF);
            acc += ((g0 + g1) + (g2 + g3)) + ((g4 + g5) + (g6 + g7));
        }
        for (; i < e; ++i)
            acc += *(const floatx4*)(prow + (size_t)edge_path[i] * NF);
        short4v xb;
        #pragma unroll
        for (int q = 0; q < 4; ++q) xb[q] = f2b(acc[q]);
        *(short4v*)(&xs[(b * 8 + cl) * XROW + fq * 4]) = xb;
    }
    __syncthreads();

    const int quad = lane >> 4;
    const int n16  = lane & 15;
    const int k0   = quad * 8;

    const int rA = w * 16 + n16;
    short8 ax = *(const short8*)(&xs[rA * XROW + k0]);
    const int bA = rA >> 3;
    const int cA = cblk + (rA & 7);
    const float* hrow = hbuf + ((size_t)bA * NC + cA) * NF + k0;
    floatx4 h0 = *(const floatx4*)(hrow);
    floatx4 h1 = *(const floatx4*)(hrow + 4);
    short8 ah;
    #pragma unroll
    for (int q = 0; q < 4; ++q) { ah[q] = f2b(h0[q]); ah[4 + q] = f2b(h1[q]); }

    float bxv[6], bhv[6];
    #pragma unroll
    for (int tt = 0; tt < 6; ++tt) {
        bxv[tt] = b_ih[16 * tt + n16];
        bhv[tt] = b_hh[16 * tt + n16];
    }
    const floatx4 zero = {0.f, 0.f, 0.f, 0.f};
    floatx4 g[4];
    #pragma unroll
    for (int tt = 0; tt < 4; ++tt) {
        short8 bw = *(const short8*)(&wsx[(16 * tt + n16) * XROW + k0]);
        floatx4 a = __builtin_amdgcn_mfma_f32_16x16x32_bf16(ax, bw, zero, 0, 0, 0);
        bw = *(const short8*)(&wsh[(16 * tt + n16) * XROW + k0]);
        g[tt] = __builtin_amdgcn_mfma_f32_16x16x32_bf16(ah, bw, a, 0, 0, 0);
    }
    floatx4 nx[2], nh[2];
    #pragma unroll
    for (int u = 0; u < 2; ++u) {
        const int tt = 4 + u;
        short8 bw = *(const short8*)(&wsx[(16 * tt + n16) * XROW + k0]);
        nx[u] = __builtin_amdgcn_mfma_f32_16x16x32_bf16(ax, bw, zero, 0, 0, 0);
        bw = *(const short8*)(&wsh[(16 * tt + n16) * XROW + k0]);
        nh[u] = __builtin_amdgcn_mfma_f32_16x16x32_bf16(ah, bw, zero, 0, 0, 0);
    }
    #pragma unroll
    for (int i = 0; i < 4; ++i) {
        const int r  = w * 16 + quad * 4 + i;
        const int b2 = r >> 3;
        const size_t m = (size_t)b2 * NC + (cblk + (r & 7));
        float r0 = sigmoidf_(g[0][i] + bxv[0] + bhv[0]);
        float r1 = sigmoidf_(g[1][i] + bxv[1] + bhv[1]);
        float z0 = sigmoidf_(g[2][i] + bxv[2] + bhv[2]);
        float z1 = sigmoidf_(g[3][i] + bxv[3] + bhv[3]);
        float n0 = tanhf_(nx[0][i] + bxv[4] + r0 * (nh[0][i] + bhv[4]));
        float n1 = tanhf_(nx[1][i] + bxv[5] + r1 * (nh[1][i] + bhv[5]));
        float hv0 = hbuf[m * NF + n16];
        float hv1 = hbuf[m * NF + 16 + n16];
        out[m * NF + n16]      = (1.f - z0) * n0 + z0 * hv0;
        out[m * NF + 16 + n16] = (1.f - z1) * n1 + z1 * hv1;
    }
}

extern "C" void kernel_launch(void* const* d_in, const int* in_sizes, int n_in,
                              void* d_out, int out_size, void* d_ws, size_t ws_size,
                              hipStream_t stream) {
    const float* path = (const float*)d_in[0];  // [8,65536,32] fp32
    const float* chan = (const float*)d_in[1];  // [8,32768,32] fp32
    const float* W_ih = (const float*)d_in[2];  // [96,32]
    const float* W_hh = (const float*)d_in[3];  // [96,32]
    const float* b_ih = (const float*)d_in[4];  // [96]
    const float* b_hh = (const float*)d_in[5];  // [96]
    const int* edge_path    = (const int*)d_in[6];
    const int* edge_channel = (const int*)d_in[7];
    float* out = (float*)d_out;                 // [8,32768,32] fp32

    const size_t pathH_bytes = (size_t)NB * NP * NF * sizeof(__half);   // 32MB
    const size_t bounds_bytes = (size_t)(NC + 1) * sizeof(int);
    const size_t wb_bytes = (size_t)2 * 96 * NF * sizeof(unsigned short); // 12KB
    const size_t need = pathH_bytes + bounds_bytes + wb_bytes;
    if (ws_size >= need) {
        __half* pathH = (__half*)d_ws;
        int* bounds = (int*)((char*)d_ws + pathH_bytes);
        unsigned short* wb = (unsigned short*)((char*)d_ws + pathH_bytes + bounds_bytes);
        const int bblocks = (NC + 1 + 255) / 256;    // 129
        prep_kernel<<<dim3(CONV_BLOCKS + bblocks + 1), dim3(256), 0, stream>>>(
            path, pathH, edge_channel, bounds, W_ih, W_hh, wb);
        fused_gru_new<<<dim3((NC / CHB) * NB), dim3(512), 0, stream>>>(
            pathH, chan, wb, b_ih, b_hh, edge_path, bounds, out);
    } else {
        fused_gru_fb<<<dim3(NC / 8), dim3(256), 0, stream>>>(
            path, chan, W_ih, W_hh, b_ih, b_hh, edge_path, edge_channel, out);
    }
}